// Round 11
// baseline (473.107 us; speedup 1.0000x reference)
//
#include <hip/hip_runtime.h>
#include <hip/hip_bf16.h>

typedef __hip_bfloat16 bf16;
typedef __attribute__((ext_vector_type(8))) short short8;
typedef __attribute__((ext_vector_type(4))) float f32x4;

__device__ __forceinline__ float b2f(bf16 v){ return __bfloat162float(v); }
__device__ __forceinline__ bf16  f2b(float v){ return __float2bfloat16(v); }
__device__ __forceinline__ unsigned short f2bu(float f){
  return __builtin_bit_cast(unsigned short, __float2bfloat16(f));
}
__device__ __forceinline__ float u2f(unsigned short u){
  return __uint_as_float(((unsigned int)u) << 16);
}
__device__ __forceinline__ unsigned int packbf(float a, float b){
  return (unsigned int)f2bu(a) | ((unsigned int)f2bu(b) << 16);
}
// fast gelu: tanh form, overflow-safe. max |err| vs erf ~8e-4
__device__ __forceinline__ float geluf(float x){
  float t = 0.7978845608028654f*(x + 0.044715f*x*x*x);
  float e = __expf(2.f*t);
  float th = 1.f - 2.f/(e + 1.f);
  return 0.5f*x*(1.f + th);
}

template<bool F32> __device__ __forceinline__ float ldin(const void* p, size_t i){
  if (F32) return ((const float*)p)[i];
  return b2f(((const bf16*)p)[i]);
}
__device__ __forceinline__ float ldf(const void* p, size_t i, bool f32){
  return f32 ? ((const float*)p)[i] : b2f(((const bf16*)p)[i]);
}

#define SS    4096      // 64*64
#define SSS   262144    // 64^3

// ---------------- dtype probe ----------------
__global__ void k_probe(const unsigned short* __restrict__ xr, int* __restrict__ flag){
  float m = 0.f;
  for (int i = threadIdx.x; i < 512; i += 64){
    unsigned int u = ((unsigned int)xr[i]) << 16;
    float v = fabsf(__uint_as_float(u));
    if (!(v < 3.0e38f)) v = 3.0e38f;
    m = fmaxf(m, v);
  }
  #pragma unroll
  for (int off = 32; off > 0; off >>= 1) m = fmaxf(m, __shfl_down(m, off));
  if (threadIdx.x == 0) flag[0] = (m > 1000.0f) ? 1 : 0;
}

// ---------------- block reduction helper ----------------
__device__ __forceinline__ void blk_reduce2(float& s, float& s2){
  __shared__ float sa[4], sb[4];
  #pragma unroll
  for (int off = 32; off > 0; off >>= 1){ s += __shfl_down(s, off); s2 += __shfl_down(s2, off); }
  int wid = threadIdx.x >> 6;
  if ((threadIdx.x & 63) == 0){ sa[wid] = s; sb[wid] = s2; }
  __syncthreads();
  if (threadIdx.x == 0){ s = sa[0]+sa[1]+sa[2]+sa[3]; s2 = sb[0]+sb[1]+sb[2]+sb[3]; }
}

// ---------------- x stats ----------------
__global__ __launch_bounds__(256) void k_cstats(const int* __restrict__ flag,
    const void* __restrict__ x, float* __restrict__ part){
  const bool f32 = (flag[0] != 0);
  int bc = blockIdx.x >> 3, sp = blockIdx.x & 7;
  size_t base = (size_t)bc*SSS + (size_t)sp*32768;
  float s = 0.f, s2 = 0.f;
  if (f32){
    const float4* p = (const float4*)((const float*)x + base);
    for (int i = threadIdx.x; i < 8192; i += 256){
      float4 v = p[i];
      s += v.x+v.y+v.z+v.w; s2 += v.x*v.x+v.y*v.y+v.z*v.z+v.w*v.w;
    }
  } else {
    const ushort4* p = (const ushort4*)((const unsigned short*)x + base);
    for (int i = threadIdx.x; i < 8192; i += 256){
      ushort4 v = p[i];
      float a=u2f(v.x),b_=u2f(v.y),c=u2f(v.z),d=u2f(v.w);
      s += a+b_+c+d; s2 += a*a+b_*b_+c*c+d*d;
    }
  }
  blk_reduce2(s, s2);
  if (threadIdx.x == 0){ part[blockIdx.x*2] = s; part[blockIdx.x*2+1] = s2; }
}

__global__ void k_sfinal(const float* __restrict__ part,
    float* __restrict__ meanH, float* __restrict__ rstdH,
    float* __restrict__ mean2, float* __restrict__ rstd2){
  int t = threadIdx.x; if (t >= 128) return;
  float s = 0.f, s2 = 0.f;
  #pragma unroll
  for (int i = 0; i < 8; i++){ s += part[(t*8+i)*2]; s2 += part[(t*8+i)*2+1]; }
  float m = s * (1.f/262144.f);
  float var = s2 * (1.f/262144.f) - m*m;
  int b = t >> 6, c = t & 63;
  if (c < 32){ meanH[b*32+c] = m; rstdH[b*32+c] = rsqrtf(var + 1e-5f); }
  else       { mean2[t] = m;      rstd2[t] = rsqrtf(var + 1e-5f); }
}

// ---------------- multiplier chain stage 1 ----------------
__global__ __launch_bounds__(256) void k_mult1(const int* __restrict__ flag,
    const void* __restrict__ p_xy, const void* __restrict__ p_zx, const void* __restrict__ p_zy,
    const void* __restrict__ xy_dw_w, const void* __restrict__ xy_dw_b,
    const void* __restrict__ zx_dw_w, const void* __restrict__ zx_dw_b,
    const void* __restrict__ zy_dw_w, const void* __restrict__ zy_dw_b,
    float* __restrict__ t_xy, float* __restrict__ t_zx, float* __restrict__ t_zy){
  const bool f32 = (flag[0] != 0);
  const float SC = 31.f/63.f;
  int id = blockIdx.x*256 + threadIdx.x;
  if (id < 32768){
    int c = id >> 12, rem = id & 4095, uu = rem >> 6, vv = rem & 63;
    float acc = ldf(xy_dw_b, c, f32);
    for (int du = 0; du < 3; du++){
      int ui = uu + du - 1; if (ui < 0 || ui >= 64) continue;
      float pu = ui*SC; int i0 = (int)pu; float wu = pu - (float)i0; int i1 = min(i0+1, 31);
      for (int dv = 0; dv < 3; dv++){
        int vi = vv + dv - 1; if (vi < 0 || vi >= 64) continue;
        float pv = vi*SC; int j0 = (int)pv; float wv = pv - (float)j0; int j1 = min(j0+1, 31);
        float s = ldf(p_xy, c*1024+i0*32+j0, f32)*(1.f-wu)*(1.f-wv) + ldf(p_xy, c*1024+i0*32+j1, f32)*(1.f-wu)*wv
                + ldf(p_xy, c*1024+i1*32+j0, f32)*wu*(1.f-wv)       + ldf(p_xy, c*1024+i1*32+j1, f32)*wu*wv;
        acc += ldf(xy_dw_w, c*9 + du*3 + dv, f32) * s;
      }
    }
    t_xy[id] = geluf(acc);
  } else if (id < 33280){
    int k = id - 32768; int c = k >> 6, a = k & 63;
    float acc = ldf(zx_dw_b, c, f32);
    for (int da = 0; da < 3; da++){
      int ai = a + da - 1; if (ai < 0 || ai >= 64) continue;
      float pa = ai*SC; int i0 = (int)pa; float wa = pa - (float)i0; int i1 = min(i0+1, 31);
      float s = ldf(p_zx, c*32+i0, f32)*(1.f-wa) + ldf(p_zx, c*32+i1, f32)*wa;
      acc += ldf(zx_dw_w, c*3+da, f32) * s;
    }
    t_zx[k] = geluf(acc);
  } else if (id < 33792){
    int k = id - 33280; int c = k >> 6, a = k & 63;
    float acc = ldf(zy_dw_b, c, f32);
    for (int da = 0; da < 3; da++){
      int ai = a + da - 1; if (ai < 0 || ai >= 64) continue;
      float pa = ai*SC; int i0 = (int)pa; float wa = pa - (float)i0; int i1 = min(i0+1, 31);
      float s = ldf(p_zy, c*32+i0, f32)*(1.f-wa) + ldf(p_zy, c*32+i1, f32)*wa;
      acc += ldf(zy_dw_w, c*3+da, f32) * s;
    }
    t_zy[k] = geluf(acc);
  }
}

// ---------------- multiplier chain stage 2 ----------------
__global__ __launch_bounds__(256) void k_mult2(const int* __restrict__ flag,
    const float* __restrict__ t_xy, const float* __restrict__ t_zx, const float* __restrict__ t_zy,
    const void* __restrict__ xy_pw_w, const void* __restrict__ xy_pw_b,
    const void* __restrict__ zx_pw_w, const void* __restrict__ zx_pw_b,
    const void* __restrict__ zy_pw_w, const void* __restrict__ zy_pw_b,
    float* __restrict__ kxy, float* __restrict__ kz, float* __restrict__ ky){
  const bool f32 = (flag[0] != 0);
  int id = blockIdx.x*256 + threadIdx.x;
  if (id < 32768){
    int oc = id >> 12, pix = id & 4095;
    float acc = ldf(xy_pw_b, oc, f32);
    #pragma unroll
    for (int ic = 0; ic < 8; ic++) acc += ldf(xy_pw_w, oc*8+ic, f32) * t_xy[ic*4096 + pix];
    kxy[id] = acc;
  } else if (id < 33280){
    int k = id - 32768; int oc = k >> 6, a = k & 63;
    float acc = ldf(zx_pw_b, oc, f32);
    #pragma unroll
    for (int ic = 0; ic < 8; ic++) acc += ldf(zx_pw_w, oc*8+ic, f32) * t_zx[ic*64 + a];
    kz[k] = acc;
  } else if (id < 33792){
    int k = id - 33280; int oc = k >> 6, a = k & 63;
    float acc = ldf(zy_pw_b, oc, f32);
    #pragma unroll
    for (int ic = 0; ic < 8; ic++) acc += ldf(zy_pw_w, oc*8+ic, f32) * t_zy[ic*64 + a];
    ky[k] = acc;
  }
}

// ---------------- fused G: TB=8, d-pair vectorized LDS ----------------
// LDS: xs[32][10][64] 40KB + t4g[8][12][64] 12KB + muinv 5KB + sw 2.8KB = ~60KB -> 2 blocks/CU.
#define TB 8
#define W_M    0
#define W_R    32
#define W_G1   64
#define W_B1   96
#define W_G2   128
#define W_B2   160
#define W_LDWB 192
#define W_LPWB 224
#define W_PW   256
#define W_PWB  320
#define W_DW   328
#define W_DWB  400
#define W_LDW  408
#define W_TOT  696

template<bool F32>
__global__ __launch_bounds__(256) void k_g(const int* __restrict__ flag,
    const void* __restrict__ x,
    const void* n1g_, const void* n1b_, const void* n2g_, const void* n2b_,
    const void* dwpw_w, const void* dwpw_b, const void* dwdw_w, const void* dwdw_b,
    const void* ldw_dw_w, const void* ldw_dw_b, const void* ldw_pw_w, const void* ldw_pw_b,
    const float* __restrict__ meanH, const float* __restrict__ rstdH,
    const float* __restrict__ kxy, const float* __restrict__ kz, const float* __restrict__ ky,
    bf16* __restrict__ g){
  if (flag[0] != (F32 ? 1 : 0)) return;
  __shared__ unsigned short xs[32*10*64];    // [c][rx10][64]; later gdbuf [512][40]
  __shared__ unsigned short t4g[8*12*64];    // [ic][rt12][64]; later lpwB [32][40]
  __shared__ float muinv[2*10*64];           // mu plane [0..639], inv plane [640..1279]
  __shared__ float sw[W_TOT];
  int n  = blockIdx.x >> 3;            // 8 tiles of TB=8 rows
  int a0 = (blockIdx.x & 7) * TB;
  int b = n & 1, h = n >> 1;
  int t = threadIdx.x;
  if (t < 32){
    sw[W_M+t]=meanH[b*32+t]; sw[W_R+t]=rstdH[b*32+t];
    sw[W_G1+t]=ldin<F32>(n1g_, t); sw[W_B1+t]=ldin<F32>(n1b_, t);
    sw[W_G2+t]=ldin<F32>(n2g_, t); sw[W_B2+t]=ldin<F32>(n2b_, t);
    sw[W_LDWB+t]=ldin<F32>(ldw_dw_b, t); sw[W_LPWB+t]=ldin<F32>(ldw_pw_b, t);
  }
  if (t >= 64 && t < 128) sw[W_PW+t-64]=ldin<F32>(dwpw_w, t-64);
  if (t >= 128 && t < 200) sw[W_DW+t-128]=ldin<F32>(dwdw_w, t-128);
  if (t >= 200 && t < 208) sw[W_PWB+t-200]=ldin<F32>(dwpw_b, t-200);
  if (t >= 208 && t < 216) sw[W_DWB+t-208]=ldin<F32>(dwdw_b, t-208);
  for (int i = t; i < 288; i += 256)  sw[W_LDW+i] = ldin<F32>(ldw_dw_w, i);
  __syncthreads();
  const float* s_g1 = sw+W_G1; const float* s_b1 = sw+W_B1;
  const float* s_g2 = sw+W_G2; const float* s_b2 = sw+W_B2;
  const size_t xbase = (size_t)b*64*SSS + (size_t)h*64;

  // stage xs rows a0-1 .. a0+8 (10 rows) = normalized x, vectorized
  for (int i = t; i < 5120; i += 256){
    int c = i / 160, rem = i - c*160, rx = rem >> 4, q = rem & 15;
    int a = a0 - 1 + rx;
    unsigned short o0=0,o1=0,o2=0,o3=0;
    if (a >= 0 && a < 64){
      float m = sw[W_M+c], r = sw[W_R+c];
      size_t base = xbase + (size_t)c*SSS + (size_t)a*SS + q*4;
      if (F32){
        float4 v = *(const float4*)((const float*)x + base);
        o0=f2bu((v.x-m)*r); o1=f2bu((v.y-m)*r); o2=f2bu((v.z-m)*r); o3=f2bu((v.w-m)*r);
      } else {
        ushort4 v = *(const ushort4*)((const unsigned short*)x + base);
        o0=f2bu((u2f(v.x)-m)*r); o1=f2bu((u2f(v.y)-m)*r); o2=f2bu((u2f(v.z)-m)*r); o3=f2bu((u2f(v.w)-m)*r);
      }
    }
    ushort4 o4; o4.x=o0; o4.y=o1; o4.z=o2; o4.w=o3;
    *(ushort4*)&xs[(c*10+rx)*64 + q*4] = o4;
  }
  __syncthreads();

  // phase 1: t4g for 12 rows (a0-2..a0+9); rt 1..10 from xs (cache mu/inv), rt 0,11 streamed
  for (int i = t; i < 384; i += 256){
    int rt = i >> 5, dp = (i & 31) << 1;
    int a = a0 - 2 + rt;
    if (a < 0 || a >= 64){
      #pragma unroll
      for (int ic = 0; ic < 8; ic++) *(unsigned int*)&t4g[(ic*12+rt)*64+dp] = 0u;
      continue;
    }
    float sumA=0.f,sqA=0.f,sumB=0.f,sqB=0.f;
    float z24A[8], z24B[8];
    if (rt >= 1 && rt <= 10){
      int rx = rt - 1;
      #pragma unroll
      for (int c = 0; c < 32; c++){
        unsigned int v = *(const unsigned int*)&xs[(c*10+rx)*64+dp];
        float va = u2f((unsigned short)v), vb = u2f((unsigned short)(v>>16));
        sumA += va; sqA += va*va; sumB += vb; sqB += vb*vb;
        if (c >= 24){ z24A[c-24]=va; z24B[c-24]=vb; }
      }
    } else {
      size_t xi = xbase + (size_t)a*SS + dp;
      #pragma unroll
      for (int c = 0; c < 32; c++){
        float va, vb;
        if (F32){
          float2 v = *(const float2*)((const float*)x + xi + (size_t)c*SSS);
          va = v.x; vb = v.y;
        } else {
          ushort2 v = *(const ushort2*)((const unsigned short*)x + xi + (size_t)c*SSS);
          va = u2f(v.x); vb = u2f(v.y);
        }
        va = (va - sw[W_M+c])*sw[W_R+c]; vb = (vb - sw[W_M+c])*sw[W_R+c];
        sumA += va; sqA += va*va; sumB += vb; sqB += vb*vb;
        if (c >= 24){ z24A[c-24]=va; z24B[c-24]=vb; }
      }
    }
    float muA = sumA*(1.f/32.f), muB = sumB*(1.f/32.f);
    float invA = rsqrtf(sqA*(1.f/32.f)-muA*muA+1e-6f);
    float invB = rsqrtf(sqB*(1.f/32.f)-muB*muB+1e-6f);
    if (rt >= 1 && rt <= 10){
      int rx = rt - 1;
      muinv[rx*64+dp] = muA;       muinv[rx*64+dp+1] = muB;
      muinv[640+rx*64+dp] = invA;  muinv[640+rx*64+dp+1] = invB;
    }
    float zlA[8], zlB[8];
    #pragma unroll
    for (int j = 0; j < 8; j++){
      zlA[j] = (z24A[j]-muA)*invA*s_g1[24+j] + s_b1[24+j];
      zlB[j] = (z24B[j]-muB)*invB*s_g1[24+j] + s_b1[24+j];
    }
    #pragma unroll
    for (int ic = 0; ic < 8; ic++){
      float aA = sw[W_PWB+ic], aB = aA;
      #pragma unroll
      for (int j = 0; j < 8; j++){ aA += sw[W_PW+ic*8+j]*zlA[j]; aB += sw[W_PW+ic*8+j]*zlB[j]; }
      *(unsigned int*)&t4g[(ic*12+rt)*64+dp] = packbf(geluf(aA), geluf(aB));
    }
  }
  __syncthreads();

  // phase 2: in-place transform of xs rows 0..9 (a = a0-1 .. a0+8)
  for (int i = t; i < 320; i += 256){
    int rx = i >> 5, dp = (i & 31) << 1;
    int a = a0 - 1 + rx;
    if (a < 0 || a >= 64) continue;      // stays zero (conv padding)
    float muA = muinv[rx*64+dp],      muB = muinv[rx*64+dp+1];
    float invA = muinv[640+rx*64+dp], invB = muinv[640+rx*64+dp+1];
    float sA=0.f,qA=0.f,sB=0.f,qB=0.f;
    #pragma unroll
    for (int c = 0; c < 8; c++){
      int idx = (c*10+rx)*64+dp;
      unsigned int v = *(const unsigned int*)&xs[idx];
      float2 kk = *(const float2*)&kxy[(c*64+a)*64+dp];
      float uA = ((u2f((unsigned short)v)-muA)*invA*s_g1[c] + s_b1[c]) * kk.x;
      float uB = ((u2f((unsigned short)(v>>16))-muB)*invB*s_g1[c] + s_b1[c]) * kk.y;
      *(unsigned int*)&xs[idx] = packbf(uA, uB);
      sA+=uA; qA+=uA*uA; sB+=uB; qB+=uB*uB;
    }
    #pragma unroll
    for (int c = 8; c < 16; c++){
      int idx = (c*10+rx)*64+dp;
      unsigned int v = *(const unsigned int*)&xs[idx];
      float kzv = kz[(c-8)*64 + a];
      float uA = ((u2f((unsigned short)v)-muA)*invA*s_g1[c] + s_b1[c]) * kzv;
      float uB = ((u2f((unsigned short)(v>>16))-muB)*invB*s_g1[c] + s_b1[c]) * kzv;
      *(unsigned int*)&xs[idx] = packbf(uA, uB);
      sA+=uA; qA+=uA*uA; sB+=uB; qB+=uB*uB;
    }
    #pragma unroll
    for (int c = 16; c < 24; c++){
      int idx = (c*10+rx)*64+dp;
      unsigned int v = *(const unsigned int*)&xs[idx];
      float2 kk = *(const float2*)&ky[(c-16)*64+dp];
      float uA = ((u2f((unsigned short)v)-muA)*invA*s_g1[c] + s_b1[c]) * kk.x;
      float uB = ((u2f((unsigned short)(v>>16))-muB)*invB*s_g1[c] + s_b1[c]) * kk.y;
      *(unsigned int*)&xs[idx] = packbf(uA, uB);
      sA+=uA; qA+=uA*uA; sB+=uB; qB+=uB*uB;
    }
    #pragma unroll
    for (int oc = 0; oc < 8; oc++){
      float accA = sw[W_DWB+oc], accB = accA;
      #pragma unroll
      for (int du = 0; du < 3; du++){
        int tb = (oc*12 + (rx+du))*64;
        unsigned int mid = *(const unsigned int*)&t4g[tb+dp];
        unsigned int lft = (dp > 0)  ? *(const unsigned int*)&t4g[tb+dp-2] : 0u;
        unsigned int rgt = (dp < 62) ? *(const unsigned int*)&t4g[tb+dp+2] : 0u;
        float l1 = u2f((unsigned short)(lft>>16));
        float m0 = u2f((unsigned short)mid), m1 = u2f((unsigned short)(mid>>16));
        float r0 = u2f((unsigned short)rgt);
        float w0 = sw[W_DW+oc*9+du*3+0], w1 = sw[W_DW+oc*9+du*3+1], w2 = sw[W_DW+oc*9+du*3+2];
        accA += w0*l1 + w1*m0 + w2*m1;
        accB += w0*m0 + w1*m1 + w2*r0;
      }
      *(unsigned int*)&xs[((24+oc)*10+rx)*64+dp] = packbf(accA, accB);
      sA+=accA; qA+=accA*accA; sB+=accB; qB+=accB*accB;
    }
    float mu2A = sA*(1.f/32.f), mu2B = sB*(1.f/32.f);
    float inv2A = rsqrtf(qA*(1.f/32.f)-mu2A*mu2A+1e-6f);
    float inv2B = rsqrtf(qB*(1.f/32.f)-mu2B*mu2B+1e-6f);
    #pragma unroll
    for (int c = 0; c < 32; c++){
      int idx = (c*10+rx)*64+dp;
      unsigned int v = *(const unsigned int*)&xs[idx];
      float nA = (u2f((unsigned short)v)-mu2A)*inv2A*s_g2[c] + s_b2[c];
      float nB = (u2f((unsigned short)(v>>16))-mu2B)*inv2B*s_g2[c] + s_b2[c];
      *(unsigned int*)&xs[idx] = packbf(nA, nB);
    }
  }
  __syncthreads();

  // phase 3a: stage lpw bf16 into t4g region; ldw dw3x3 + gelu -> packed regs
  unsigned short* lpwB = t4g;        // [32 oc][40]
  unsigned short* gdXS = xs;         // later [512 px][40]
  for (int i = t; i < 1024; i += 256){
    int o = i >> 5, ic = i & 31;
    lpwB[o*40 + ic] = f2bu(ldin<F32>(ldw_pw_w, o*32+ic));
  }
  unsigned int gdp[32];
  {
    int row = t >> 5, dp = (t & 31) << 1;   // output rows a0+row, pixels dp, dp+1
    #pragma unroll
    for (int oc = 0; oc < 32; oc++){
      float accA = sw[W_LDWB+oc], accB = accA;
      #pragma unroll
      for (int du = 0; du < 3; du++){
        int xb = (oc*10 + (row+du))*64;     // tap xs rows row..row+2
        unsigned int mid = *(const unsigned int*)&xs[xb+dp];
        unsigned int lft = (dp > 0)  ? *(const unsigned int*)&xs[xb+dp-2] : 0u;
        unsigned int rgt = (dp < 62) ? *(const unsigned int*)&xs[xb+dp+2] : 0u;
        float l1 = u2f((unsigned short)(lft>>16));
        float m0 = u2f((unsigned short)mid), m1 = u2f((unsigned short)(mid>>16));
        float r0 = u2f((unsigned short)rgt);
        float w0 = sw[W_LDW+oc*9+du*3+0], w1 = sw[W_LDW+oc*9+du*3+1], w2 = sw[W_LDW+oc*9+du*3+2];
        accA += w0*l1 + w1*m0 + w2*m1;
        accB += w0*m0 + w1*m1 + w2*r0;
      }
      gdp[oc] = packbf(geluf(accA), geluf(accB));
    }
  }
  __syncthreads();     // all xs conv reads + lpwB writes done

  // write gdbuf over xs: [512][40], rows px0=row*64+dp (lo halves), px0+1 (hi halves)
  {
    int row = t >> 5, dp = (t & 31) << 1;
    int px0 = row*64 + dp;
    #pragma unroll
    for (int k = 0; k < 16; k++){
      unsigned int w0 = (gdp[2*k] & 0xffffu) | (gdp[2*k+1] << 16);
      unsigned int w1 = (gdp[2*k] >> 16)     | (gdp[2*k+1] & 0xffff0000u);
      *(unsigned int*)&gdXS[px0*40 + 2*k]     = w0;
      *(unsigned int*)&gdXS[(px0+1)*40 + 2*k] = w1;
    }
  }
  __syncthreads();

  // phase 3b: MFMA pointwise 512px x 32oc, K=32
  {
    int wv = t >> 6, l = t & 63;
    int lr = l & 15, lg = l >> 4;
    #pragma unroll
    for (int mi = 0; mi < 8; mi++){
      int px0 = wv*128 + mi*16;
      short8 af = *(const short8*)&gdXS[(px0+lr)*40 + lg*8];
      #pragma unroll
      for (int ot = 0; ot < 2; ot++){
        short8 bfg = *(const short8*)&lpwB[(ot*16+lr)*40 + lg*8];
        f32x4 c4 = {0.f,0.f,0.f,0.f};
        c4 = __builtin_amdgcn_mfma_f32_16x16x32_bf16(af, bfg, c4, 0, 0, 0);
        int oc = ot*16 + lr;
        float bo = sw[W_LPWB+oc];
        #pragma unroll
        for (int r4 = 0; r4 < 4; r4++){
          int px = px0 + lg*4 + r4;
          int aa = a0 + (px >> 6), dd = px & 63;
          g[(size_t)n*131072 + (size_t)oc*4096 + aa*64 + dd] = f2b(c4[r4] + bo);
        }
      }
    }
  }
}

// ---------------- g-half stats2 partials ----------------
__global__ __launch_bounds__(256) void k_gstats(const bf16* __restrict__ g,
                                                float* __restrict__ partg){
  int pair = blockIdx.x >> 3, sp = blockIdx.x & 7;
  int b = pair >> 5, c = pair & 31;
  float s = 0.f, s2 = 0.f;
  for (int i = threadIdx.x; i < 32768; i += 256){
    int ii = sp*32768 + i;
    int d = ii & 63, w = (ii >> 6) & 63, h = ii >> 12;
    int n1 = h*2 + b, n2 = (63-h)*2 + b;
    float v = b2f(g[((size_t)n1*32 + c)*4096 + w*64 + d]) + b2f(g[((size_t)n2*32 + c)*4096 + w*64 + d]);
    s += v; s2 += v*v;
  }
  blk_reduce2(s, s2);
  if (threadIdx.x == 0){ partg[blockIdx.x*2] = s; partg[blockIdx.x*2+1] = s2; }
}

__global__ void k_gfinal(const float* __restrict__ partg,
                         float* __restrict__ mean2, float* __restrict__ rstd2){
  int t = threadIdx.x; if (t >= 64) return;
  float s = 0.f, s2 = 0.f;
  #pragma unroll
  for (int i = 0; i < 8; i++){ s += partg[(t*8+i)*2]; s2 += partg[(t*8+i)*2+1]; }
  float m = s * (1.f/262144.f);
  float var = s2 * (1.f/262144.f) - m*m;
  int b = t >> 5, c = t & 31;
  mean2[b*64+c] = m; rstd2[b*64+c] = rsqrtf(var + 1e-5f);
}

// ---------------- mprep ----------------
__global__ __launch_bounds__(256) void k_mprep(const int* __restrict__ flag,
    const void* __restrict__ fc1w, const void* __restrict__ fc1b,
    const void* __restrict__ fc2w, const void* __restrict__ fc2b,
    const float* __restrict__ mean2, const float* __restrict__ rstd2,
    unsigned short* __restrict__ W1p, unsigned short* __restrict__ W2b,
    float* __restrict__ b1p, float* __restrict__ b2p){
  const bool f32 = (flag[0] != 0);
  int gid = blockIdx.x*256 + threadIdx.x;
  for (int i = gid; i < 16384; i += 4096){
    int bb = i >> 13, r = i & 8191, c = r & 63;
    W1p[i] = f2bu(ldf(fc1w, r, f32) * rstd2[bb*64+c]);
  }
  for (int i = gid; i < 8192; i += 4096) W2b[i] = f2bu(ldf(fc2w, i, f32));
  if (gid < 256){
    int bb = gid >> 7, j = gid & 127;
    float s = ldf(fc1b, j, f32);
    for (int c = 0; c < 64; c++) s -= ldf(fc1w, j*64+c, f32) * mean2[bb*64+c] * rstd2[bb*64+c];
    b1p[gid] = s;
  }
  if (gid < 64) b2p[gid] = ldf(fc2b, gid, f32);
}

// ---------------- MFMA MLP (unchanged from r10) ----------------
__global__ __launch_bounds__(256) void k_mlp(const int* __restrict__ flag,
    const void* __restrict__ x, const bf16* __restrict__ g,
    const unsigned short* __restrict__ W1p, const unsigned short* __restrict__ W2b,
    const float* __restrict__ b1p, const float* __restrict__ b2p,
    void* __restrict__ out){
  const bool f32 = (flag[0] != 0);
  __shared__ char smem[54272];
  unsigned short* zs  = (unsigned short*)smem;
  unsigned short* hb  = (unsigned short*)smem;
  unsigned short* w1s = (unsigned short*)(smem+18432);
  unsigned short* w2s = (unsigned short*)(smem+36864);
  float* obuf = (float*)smem;
  int blk = blockIdx.x;
  int b = blk >> 11, w = (blk >> 5) & 63, hblk = blk & 31;
  int h0 = hblk*2;
  int t = threadIdx.x;
  int wv = t >> 6, l = t & 63;
  int lr = l & 15, lg = l >> 4;

  const unsigned short* W1g = W1p + b*8192;
  for (int i = t; i < 1024; i += 256){
    int j = i >> 3, q = i & 7;
    *(short8*)&w1s[j*72 + q*8] = *(const short8*)&W1g[j*64 + q*8];
  }
  for (int i = t; i < 1024; i += 256){
    int o = i >> 4, q = i & 15;
    *(short8*)&w2s[o*136 + q*8] = *(const short8*)&W2b[o*128 + q*8];
  }
  float bj_r[8], bo_r[4];
  #pragma unroll
  for (int jt = 0; jt < 8; jt++) bj_r[jt] = b1p[b*128 + jt*16 + lr];
  #pragma unroll
  for (int ot = 0; ot < 4; ot++) bo_r[ot] = b2p[ot*16 + lr];

  {
    int px = t & 127, half = t >> 7;
    int hh = px >> 6, d = px & 63;
    int h = h0 + hh;
    unsigned short tmp[32];
    if (half == 0){
      int n1 = h*2 + b, n2 = (63-h)*2 + b;
      const bf16* g1 = g + ((size_t)n1*32)*4096 + w*64 + d;
      const bf16* g2 = g + ((size_t)n2*32)*4096 + w*64 + d;
      #pragma unroll
      for (int c = 0; c < 32; c++) tmp[c] = f2bu(b2f(g1[(size_t)c*4096]) + b2f(g2[(size_t)c*4096]));
    } else {
      size_t xi = ((size_t)(b*64+32))*SSS + (size_t)w*4096 + (size_t)h*64 + d;
      if (f32){
        const float* xp = (const float*)x;
        #pragma unroll
        for (int c = 0; c < 32; c++) tmp[c] = f2bu(xp[xi + (size_t)c*SSS]);
      } else {
        const unsigned short* xp = (const unsigned short*)x;
        #pragma unroll
        for (int c = 0; c < 32; c++) tmp[c] = xp[xi + (size_t)c*SSS];
      }
    }
    short8* dst = (short8*)&zs[px*72 + half*32];
    #pragma unroll
    for (int q = 0; q < 4; q++) dst[q] = *(short8*)&tmp[q*8];
  }
  __syncthreads();

  short8 a0f[2], a1f[2];
  #pragma unroll
  for (int mi = 0; mi < 2; mi++){
    int px0 = wv*32 + mi*16;
    a0f[mi] = *(const short8*)&zs[(px0+lr)*72 + lg*8];
    a1f[mi] = *(const short8*)&zs[(px0+lr)*72 + 32 + lg*8];
  }
  __syncthreads();

  unsigned short* hbw = &hb[wv*16*136];
  float ov[2][4][4];
  #pragma unroll
  for (int mi = 0; mi < 2; mi++){
    f32x4 acc[8];
    #pragma unroll
    for (int jt = 0; jt < 8; jt++){
      short8 b0 = *(const short8*)&w1s[(jt*16+lr)*72 + lg*8];
      short8 b1 = *(const short8*)&w1s[(jt*16+lr)*72 + 32 + lg*8];
      f32x4 c4 = {0.f,0.f,0.f,0.f};
      c4 = __builtin_amdgcn_mfma_f32_16x16x32_bf16(a0f[mi], b0, c4, 0, 0, 0);
      c4 = __builtin_amdgcn_mfma_f32_16x16x32_bf16(a1f[mi], b1, c4, 0, 0, 0);
      acc[jt] = c4;
    }
    #pragma unroll
    for (int jt = 0; jt < 8; jt++){
      float bj = bj_r[jt];
      #pragma unroll
      for (int r = 0; r < 4; r++){
        hbw[(lg*4+r)*136 + jt*16 + lr] = f2bu(geluf(acc[jt][r] + bj));
      }
    }
    short8 ha[4];
    #pragma unroll
    for (int m = 0; m < 4; m++) ha[m] = *(const short8*)&hbw[lr*136 + m*32 + lg*8];
    #pragma unroll
    for (int ot = 0; ot < 4; ot++){
      f32x4 c4 = {0.f,0.f,0.f,0.f};
      #pragma unroll
      for (int m = 0; m < 4; m++){
        short8 bb = *(const short8*)&w2s[(ot*16+lr)*136 + m*32 + lg*8];
        c4 = __builtin_amdgcn_mfma_f32_16x16x32_bf16(ha[m], bb, c4, 0, 0, 0);
      }
      #pragma unroll
      for (int r4 = 0; r4 < 4; r4++) ov[mi][ot][r4] = c4[r4];
    }
  }
  __syncthreads();

  #pragma unroll
  for (int mi = 0; mi < 2; mi++){
    int px0 = wv*32 + mi*16;
    #pragma unroll
    for (int ot = 0; ot < 4; ot++){
      float bo = bo_r[ot];
      int oc = ot*16 + lr;
      #pragma unroll
      for (int r4 = 0; r4 < 4; r4++){
        obuf[oc*129 + px0 + lg*4 + r4] = ov[mi][ot][r4] + bo;
      }
    }
  }
  __syncthreads();

  {
    int oc = t >> 2, ch = t & 3;
    size_t base = ((size_t)(b*64+oc))*SSS + (size_t)w*4096 + (size_t)h0*64 + ch*32;
    const float* src = &obuf[oc*129 + ch*32];
    if (f32){
      float* op = (float*)out;
      #pragma unroll
      for (int k = 0; k < 8; k++){
        float4 v; v.x = src[k*4]; v.y = src[k*4+1]; v.z = src[k*4+2]; v.w = src[k*4+3];
        *(float4*)&op[base + k*4] = v;
      }
    } else {
      bf16* op = (bf16*)out;
      #pragma unroll
      for (int k = 0; k < 4; k++){
        unsigned short tmp8[8];
        #pragma unroll
        for (int j = 0; j < 8; j++) tmp8[j] = f2bu(src[k*8+j]);
        *(short8*)&op[base + k*8] = *(const short8*)tmp8;
      }
    }
  }
}

extern "C" void kernel_launch(void* const* d_in, const int* in_sizes, int n_in,
                              void* d_out, int out_size, void* d_ws, size_t ws_size,
                              hipStream_t stream) {
  const void* X      = d_in[0];
  const void* n1g    = d_in[1];
  const void* n1b    = d_in[2];
  const void* n2g    = d_in[3];
  const void* n2b    = d_in[4];
  const void* p_xy   = d_in[5];
  const void* p_zx   = d_in[6];
  const void* p_zy   = d_in[7];
  const void* xy_dw_w= d_in[8];
  const void* xy_dw_b= d_in[9];
  const void* xy_pw_w= d_in[10];
  const void* xy_pw_b= d_in[11];
  const void* zx_dw_w= d_in[12];
  const void* zx_dw_b= d_in[13];
  const void* zx_pw_w= d_in[14];
  const void* zx_pw_b= d_in[15];
  const void* zy_dw_w= d_in[16];
  const void* zy_dw_b= d_in[17];
  const void* zy_pw_w= d_in[18];
  const void* zy_pw_b= d_in[19];
  const void* dw_pw_w= d_in[20];
  const void* dw_pw_b= d_in[21];
  const void* dw_dw_w= d_in[22];
  const void* dw_dw_b= d_in[23];
  const void* ldw_dw_w=d_in[24];
  const void* ldw_dw_b=d_in[25];
  const void* ldw_pw_w=d_in[26];
  const void* ldw_pw_b=d_in[27];
  const void* fc1w   = d_in[28];
  const void* fc1b   = d_in[29];
  const void* fc2w   = d_in[30];
  const void* fc2b   = d_in[31];

  int*  flag = (int*)d_ws;
  bf16* g    = (bf16*)((char*)d_ws + 16);
  float* fb  = (float*)((char*)d_ws + 16 + (size_t)16777216*2);
  float* meanH = fb;
  float* rstdH = fb + 64;
  float* t_xy  = fb + 128;
  float* t_zx  = fb + 32896;
  float* t_zy  = fb + 33408;
  float* kxy   = fb + 33920;
  float* kz    = fb + 66688;
  float* ky    = fb + 67200;
  float* mean2 = fb + 67712;
  float* rstd2 = fb + 67840;
  float* part  = fb + 67968;
  float* partg = fb + 70016;
  float* b1p   = fb + 71040;
  float* b2p   = fb + 71296;
  unsigned short* W1p = (unsigned short*)(fb + 71360);
  unsigned short* W2b = (unsigned short*)(fb + 79552);

  k_probe<<<1, 64, 0, stream>>>((const unsigned short*)X, flag);
  k_cstats<<<1024, 256, 0, stream>>>(flag, X, part);
  k_sfinal<<<1, 128, 0, stream>>>(part, meanH, rstdH, mean2, rstd2);
  k_mult1<<<132, 256, 0, stream>>>(flag, p_xy, p_zx, p_zy, xy_dw_w, xy_dw_b,
                                   zx_dw_w, zx_dw_b, zy_dw_w, zy_dw_b, t_xy, t_zx, t_zy);
  k_mult2<<<132, 256, 0, stream>>>(flag, t_xy, t_zx, t_zy, xy_pw_w, xy_pw_b,
                                   zx_pw_w, zx_pw_b, zy_pw_w, zy_pw_b, kxy, kz, ky);
  k_g<false><<<128*(64/TB), 256, 0, stream>>>(flag, X, n1g, n1b, n2g, n2b,
                                       dw_pw_w, dw_pw_b, dw_dw_w, dw_dw_b,
                                       ldw_dw_w, ldw_dw_b, ldw_pw_w, ldw_pw_b,
                                       meanH, rstdH, kxy, kz, ky, g);
  k_g<true ><<<128*(64/TB), 256, 0, stream>>>(flag, X, n1g, n1b, n2g, n2b,
                                       dw_pw_w, dw_pw_b, dw_dw_w, dw_dw_b,
                                       ldw_dw_w, ldw_dw_b, ldw_pw_w, ldw_pw_b,
                                       meanH, rstdH, kxy, kz, ky, g);
  k_gstats<<<512, 256, 0, stream>>>(g, partg);
  k_gfinal<<<1, 64, 0, stream>>>(partg, mean2, rstd2);
  k_mprep<<<16, 256, 0, stream>>>(flag, fc1w, fc1b, fc2w, fc2b, mean2, rstd2,
                                  W1p, W2b, b1p, b2p);
  k_mlp<<<4096, 256, 0, stream>>>(flag, X, g, W1p, W2b, b1p, b2p, d_out);
}

// Round 12
// 375.560 us; speedup vs baseline: 1.2597x; 1.2597x over previous
//
#include <hip/hip_runtime.h>
#include <hip/hip_bf16.h>

typedef __hip_bfloat16 bf16;
typedef __attribute__((ext_vector_type(8))) short short8;
typedef __attribute__((ext_vector_type(4))) float f32x4;

__device__ __forceinline__ float b2f(bf16 v){ return __bfloat162float(v); }
__device__ __forceinline__ bf16  f2b(float v){ return __float2bfloat16(v); }
__device__ __forceinline__ unsigned short f2bu(float f){
  return __builtin_bit_cast(unsigned short, __float2bfloat16(f));
}
__device__ __forceinline__ float u2f(unsigned short u){
  return __uint_as_float(((unsigned int)u) << 16);
}
// fast gelu: tanh form, overflow-safe. max |err| vs erf ~8e-4
__device__ __forceinline__ float geluf(float x){
  float t = 0.7978845608028654f*(x + 0.044715f*x*x*x);
  float e = __expf(2.f*t);
  float th = 1.f - 2.f/(e + 1.f);
  return 0.5f*x*(1.f + th);
}

template<bool F32> __device__ __forceinline__ float ldin(const void* p, size_t i){
  if (F32) return ((const float*)p)[i];
  return b2f(((const bf16*)p)[i]);
}
__device__ __forceinline__ float ldf(const void* p, size_t i, bool f32){
  return f32 ? ((const float*)p)[i] : b2f(((const bf16*)p)[i]);
}

#define SS    4096      // 64*64
#define SSS   262144    // 64^3

// ---------------- dtype probe ----------------
__global__ void k_probe(const unsigned short* __restrict__ xr, int* __restrict__ flag){
  float m = 0.f;
  for (int i = threadIdx.x; i < 512; i += 64){
    unsigned int u = ((unsigned int)xr[i]) << 16;
    float v = fabsf(__uint_as_float(u));
    if (!(v < 3.0e38f)) v = 3.0e38f;
    m = fmaxf(m, v);
  }
  #pragma unroll
  for (int off = 32; off > 0; off >>= 1) m = fmaxf(m, __shfl_down(m, off));
  if (threadIdx.x == 0) flag[0] = (m > 1000.0f) ? 1 : 0;
}

// ---------------- block reduction helper ----------------
__device__ __forceinline__ void blk_reduce2(float& s, float& s2){
  __shared__ float sa[4], sb[4];
  #pragma unroll
  for (int off = 32; off > 0; off >>= 1){ s += __shfl_down(s, off); s2 += __shfl_down(s2, off); }
  int wid = threadIdx.x >> 6;
  if ((threadIdx.x & 63) == 0){ sa[wid] = s; sb[wid] = s2; }
  __syncthreads();
  if (threadIdx.x == 0){ s = sa[0]+sa[1]+sa[2]+sa[3]; s2 = sb[0]+sb[1]+sb[2]+sb[3]; }
}

// ---------------- x stats ----------------
__global__ __launch_bounds__(256) void k_cstats(const int* __restrict__ flag,
    const void* __restrict__ x, float* __restrict__ part){
  const bool f32 = (flag[0] != 0);
  int bc = blockIdx.x >> 3, sp = blockIdx.x & 7;
  size_t base = (size_t)bc*SSS + (size_t)sp*32768;
  float s = 0.f, s2 = 0.f;
  if (f32){
    const float4* p = (const float4*)((const float*)x + base);
    for (int i = threadIdx.x; i < 8192; i += 256){
      float4 v = p[i];
      s += v.x+v.y+v.z+v.w; s2 += v.x*v.x+v.y*v.y+v.z*v.z+v.w*v.w;
    }
  } else {
    const ushort4* p = (const ushort4*)((const unsigned short*)x + base);
    for (int i = threadIdx.x; i < 8192; i += 256){
      ushort4 v = p[i];
      float a=u2f(v.x),b_=u2f(v.y),c=u2f(v.z),d=u2f(v.w);
      s += a+b_+c+d; s2 += a*a+b_*b_+c*c+d*d;
    }
  }
  blk_reduce2(s, s2);
  if (threadIdx.x == 0){ part[blockIdx.x*2] = s; part[blockIdx.x*2+1] = s2; }
}

__global__ void k_sfinal(const float* __restrict__ part,
    float* __restrict__ meanH, float* __restrict__ rstdH,
    float* __restrict__ mean2, float* __restrict__ rstd2){
  int t = threadIdx.x; if (t >= 128) return;
  float s = 0.f, s2 = 0.f;
  #pragma unroll
  for (int i = 0; i < 8; i++){ s += part[(t*8+i)*2]; s2 += part[(t*8+i)*2+1]; }
  float m = s * (1.f/262144.f);
  float var = s2 * (1.f/262144.f) - m*m;
  int b = t >> 6, c = t & 63;
  if (c < 32){ meanH[b*32+c] = m; rstdH[b*32+c] = rsqrtf(var + 1e-5f); }
  else       { mean2[t] = m;      rstd2[t] = rsqrtf(var + 1e-5f); }
}

// ---------------- multiplier chain stage 1 ----------------
__global__ __launch_bounds__(256) void k_mult1(const int* __restrict__ flag,
    const void* __restrict__ p_xy, const void* __restrict__ p_zx, const void* __restrict__ p_zy,
    const void* __restrict__ xy_dw_w, const void* __restrict__ xy_dw_b,
    const void* __restrict__ zx_dw_w, const void* __restrict__ zx_dw_b,
    const void* __restrict__ zy_dw_w, const void* __restrict__ zy_dw_b,
    float* __restrict__ t_xy, float* __restrict__ t_zx, float* __restrict__ t_zy){
  const bool f32 = (flag[0] != 0);
  const float SC = 31.f/63.f;
  int id = blockIdx.x*256 + threadIdx.x;
  if (id < 32768){
    int c = id >> 12, rem = id & 4095, uu = rem >> 6, vv = rem & 63;
    float acc = ldf(xy_dw_b, c, f32);
    for (int du = 0; du < 3; du++){
      int ui = uu + du - 1; if (ui < 0 || ui >= 64) continue;
      float pu = ui*SC; int i0 = (int)pu; float wu = pu - (float)i0; int i1 = min(i0+1, 31);
      for (int dv = 0; dv < 3; dv++){
        int vi = vv + dv - 1; if (vi < 0 || vi >= 64) continue;
        float pv = vi*SC; int j0 = (int)pv; float wv = pv - (float)j0; int j1 = min(j0+1, 31);
        float s = ldf(p_xy, c*1024+i0*32+j0, f32)*(1.f-wu)*(1.f-wv) + ldf(p_xy, c*1024+i0*32+j1, f32)*(1.f-wu)*wv
                + ldf(p_xy, c*1024+i1*32+j0, f32)*wu*(1.f-wv)       + ldf(p_xy, c*1024+i1*32+j1, f32)*wu*wv;
        acc += ldf(xy_dw_w, c*9 + du*3 + dv, f32) * s;
      }
    }
    t_xy[id] = geluf(acc);
  } else if (id < 33280){
    int k = id - 32768; int c = k >> 6, a = k & 63;
    float acc = ldf(zx_dw_b, c, f32);
    for (int da = 0; da < 3; da++){
      int ai = a + da - 1; if (ai < 0 || ai >= 64) continue;
      float pa = ai*SC; int i0 = (int)pa; float wa = pa - (float)i0; int i1 = min(i0+1, 31);
      float s = ldf(p_zx, c*32+i0, f32)*(1.f-wa) + ldf(p_zx, c*32+i1, f32)*wa;
      acc += ldf(zx_dw_w, c*3+da, f32) * s;
    }
    t_zx[k] = geluf(acc);
  } else if (id < 33792){
    int k = id - 33280; int c = k >> 6, a = k & 63;
    float acc = ldf(zy_dw_b, c, f32);
    for (int da = 0; da < 3; da++){
      int ai = a + da - 1; if (ai < 0 || ai >= 64) continue;
      float pa = ai*SC; int i0 = (int)pa; float wa = pa - (float)i0; int i1 = min(i0+1, 31);
      float s = ldf(p_zy, c*32+i0, f32)*(1.f-wa) + ldf(p_zy, c*32+i1, f32)*wa;
      acc += ldf(zy_dw_w, c*3+da, f32) * s;
    }
    t_zy[k] = geluf(acc);
  }
}

// ---------------- multiplier chain stage 2 ----------------
__global__ __launch_bounds__(256) void k_mult2(const int* __restrict__ flag,
    const float* __restrict__ t_xy, const float* __restrict__ t_zx, const float* __restrict__ t_zy,
    const void* __restrict__ xy_pw_w, const void* __restrict__ xy_pw_b,
    const void* __restrict__ zx_pw_w, const void* __restrict__ zx_pw_b,
    const void* __restrict__ zy_pw_w, const void* __restrict__ zy_pw_b,
    float* __restrict__ kxy, float* __restrict__ kz, float* __restrict__ ky){
  const bool f32 = (flag[0] != 0);
  int id = blockIdx.x*256 + threadIdx.x;
  if (id < 32768){
    int oc = id >> 12, pix = id & 4095;
    float acc = ldf(xy_pw_b, oc, f32);
    #pragma unroll
    for (int ic = 0; ic < 8; ic++) acc += ldf(xy_pw_w, oc*8+ic, f32) * t_xy[ic*4096 + pix];
    kxy[id] = acc;
  } else if (id < 33280){
    int k = id - 32768; int oc = k >> 6, a = k & 63;
    float acc = ldf(zx_pw_b, oc, f32);
    #pragma unroll
    for (int ic = 0; ic < 8; ic++) acc += ldf(zx_pw_w, oc*8+ic, f32) * t_zx[ic*64 + a];
    kz[k] = acc;
  } else if (id < 33792){
    int k = id - 33280; int oc = k >> 6, a = k & 63;
    float acc = ldf(zy_pw_b, oc, f32);
    #pragma unroll
    for (int ic = 0; ic < 8; ic++) acc += ldf(zy_pw_w, oc*8+ic, f32) * t_zy[ic*64 + a];
    ky[k] = acc;
  }
}

// ---------------- fused G (r10 proven: TB=4, LDS-resident, MFMA pointwise) ----------------
#define TB 4
#define W_M    0
#define W_R    32
#define W_G1   64
#define W_B1   96
#define W_G2   128
#define W_B2   160
#define W_LDWB 192
#define W_LPWB 224
#define W_PW   256
#define W_PWB  320
#define W_DW   328
#define W_DWB  400
#define W_LDW  408
#define W_TOT  696

template<bool F32>
__global__ __launch_bounds__(256) void k_g(const int* __restrict__ flag,
    const void* __restrict__ x,
    const void* n1g_, const void* n1b_, const void* n2g_, const void* n2b_,
    const void* dwpw_w, const void* dwpw_b, const void* dwdw_w, const void* dwdw_b,
    const void* ldw_dw_w, const void* ldw_dw_b, const void* ldw_pw_w, const void* ldw_pw_b,
    const float* __restrict__ meanH, const float* __restrict__ rstdH,
    const float* __restrict__ kxy, const float* __restrict__ kz, const float* __restrict__ ky,
    bf16* __restrict__ g){
  if (flag[0] != (F32 ? 1 : 0)) return;
  __shared__ unsigned short xs[32*6*64];
  __shared__ unsigned short t4g[8*8*64];
  __shared__ float muinv[2*6*64];
  __shared__ float sw[W_TOT];
  int n  = blockIdx.x >> 4;
  int a0 = (blockIdx.x & 15) * TB;
  int b = n & 1, h = n >> 1;
  int t = threadIdx.x;
  if (t < 32){
    sw[W_M+t]=meanH[b*32+t]; sw[W_R+t]=rstdH[b*32+t];
    sw[W_G1+t]=ldin<F32>(n1g_, t); sw[W_B1+t]=ldin<F32>(n1b_, t);
    sw[W_G2+t]=ldin<F32>(n2g_, t); sw[W_B2+t]=ldin<F32>(n2b_, t);
    sw[W_LDWB+t]=ldin<F32>(ldw_dw_b, t); sw[W_LPWB+t]=ldin<F32>(ldw_pw_b, t);
  }
  if (t >= 64 && t < 128) sw[W_PW+t-64]=ldin<F32>(dwpw_w, t-64);
  if (t >= 128 && t < 200) sw[W_DW+t-128]=ldin<F32>(dwdw_w, t-128);
  if (t >= 200 && t < 208) sw[W_PWB+t-200]=ldin<F32>(dwpw_b, t-200);
  if (t >= 208 && t < 216) sw[W_DWB+t-208]=ldin<F32>(dwdw_b, t-208);
  for (int i = t; i < 288; i += 256)  sw[W_LDW+i] = ldin<F32>(ldw_dw_w, i);
  __syncthreads();
  const float* s_g1 = sw+W_G1; const float* s_b1 = sw+W_B1;
  const float* s_g2 = sw+W_G2; const float* s_b2 = sw+W_B2;
  const int arow0 = a0 - 2;
  const size_t xbase = (size_t)b*64*SSS + (size_t)h*64;

  for (int i = t; i < 3072; i += 256){
    int c = i / 96, rem = i - c*96, row = rem >> 4, q = rem & 15;
    int a = a0 - 1 + row;
    unsigned short o0=0,o1=0,o2=0,o3=0;
    if (a >= 0 && a < 64){
      float m = sw[W_M+c], r = sw[W_R+c];
      size_t base = xbase + (size_t)c*SSS + (size_t)a*SS + q*4;
      if (F32){
        float4 v = *(const float4*)((const float*)x + base);
        o0=f2bu((v.x-m)*r); o1=f2bu((v.y-m)*r); o2=f2bu((v.z-m)*r); o3=f2bu((v.w-m)*r);
      } else {
        ushort4 v = *(const ushort4*)((const unsigned short*)x + base);
        o0=f2bu((u2f(v.x)-m)*r); o1=f2bu((u2f(v.y)-m)*r); o2=f2bu((u2f(v.z)-m)*r); o3=f2bu((u2f(v.w)-m)*r);
      }
    }
    ushort4 o4; o4.x=o0; o4.y=o1; o4.z=o2; o4.w=o3;
    *(ushort4*)&xs[(c*6+row)*64 + q*4] = o4;
  }
  __syncthreads();

  for (int p = t; p < 8*64; p += 256){
    int row = p >> 6, d = p & 63;
    int a = arow0 + row;
    if (a < 0 || a >= 64){
      #pragma unroll
      for (int ic = 0; ic < 8; ic++) t4g[(ic*8+row)*64+d] = 0;
      continue;
    }
    float sum = 0.f, sq = 0.f; float z24[8];
    if (row >= 1 && row <= 6){
      int r6 = row - 1;
      #pragma unroll
      for (int c = 0; c < 32; c++){
        float v = u2f(xs[(c*6+r6)*64+d]); sum += v; sq += v*v;
        if (c >= 24) z24[c-24] = v;
      }
    } else {
      size_t xi = xbase + (size_t)a*SS + d;
      #pragma unroll
      for (int c = 0; c < 32; c++){
        float v = (ldin<F32>(x, xi + (size_t)c*SSS) - sw[W_M+c]) * sw[W_R+c];
        sum += v; sq += v*v;
        if (c >= 24) z24[c-24] = v;
      }
    }
    float mu = sum * (1.f/32.f);
    float inv = rsqrtf(sq*(1.f/32.f) - mu*mu + 1e-6f);
    if (row >= 1 && row <= 6){
      muinv[(row-1)*64+d] = mu; muinv[384 + (row-1)*64+d] = inv;
    }
    float zl[8];
    #pragma unroll
    for (int j = 0; j < 8; j++) zl[j] = (z24[j]-mu)*inv*s_g1[24+j] + s_b1[24+j];
    #pragma unroll
    for (int ic = 0; ic < 8; ic++){
      float acc = sw[W_PWB+ic];
      #pragma unroll
      for (int j = 0; j < 8; j++) acc += sw[W_PW+ic*8+j]*zl[j];
      t4g[(ic*8+row)*64+d] = f2bu(geluf(acc));
    }
  }
  __syncthreads();

  for (int p = t; p < 6*64; p += 256){
    int r2 = p >> 6, d = p & 63;
    int a = a0 - 1 + r2;
    if (a < 0 || a >= 64) continue;
    float mu = muinv[r2*64+d], inv = muinv[384 + r2*64+d];
    float s2 = 0.f, q2 = 0.f;
    #pragma unroll
    for (int c = 0; c < 8; c++){
      int idx = (c*6+r2)*64+d;
      float u = ((u2f(xs[idx])-mu)*inv*s_g1[c] + s_b1[c]) * kxy[(c*64 + a)*64 + d];
      xs[idx] = f2bu(u); s2 += u; q2 += u*u;
    }
    #pragma unroll
    for (int c = 8; c < 16; c++){
      int idx = (c*6+r2)*64+d;
      float u = ((u2f(xs[idx])-mu)*inv*s_g1[c] + s_b1[c]) * kz[(c-8)*64 + a];
      xs[idx] = f2bu(u); s2 += u; q2 += u*u;
    }
    #pragma unroll
    for (int c = 16; c < 24; c++){
      int idx = (c*6+r2)*64+d;
      float u = ((u2f(xs[idx])-mu)*inv*s_g1[c] + s_b1[c]) * ky[(c-16)*64 + d];
      xs[idx] = f2bu(u); s2 += u; q2 += u*u;
    }
    #pragma unroll
    for (int oc = 0; oc < 8; oc++){
      float acc = sw[W_DWB+oc];
      #pragma unroll
      for (int du = 0; du < 3; du++){
        #pragma unroll
        for (int dv = 0; dv < 3; dv++){
          int v2 = d + dv - 1;
          if (v2 >= 0 && v2 < 64) acc += sw[W_DW+oc*9+du*3+dv]*u2f(t4g[(oc*8+r2+du)*64+v2]);
        }
      }
      xs[((24+oc)*6+r2)*64+d] = f2bu(acc); s2 += acc; q2 += acc*acc;
    }
    float mu2 = s2 * (1.f/32.f);
    float inv2 = rsqrtf(q2*(1.f/32.f) - mu2*mu2 + 1e-6f);
    #pragma unroll
    for (int c = 0; c < 32; c++){
      int idx = (c*6+r2)*64+d;
      float uu = u2f(xs[idx]);
      xs[idx] = f2bu((uu-mu2)*inv2*s_g2[c] + s_b2[c]);
    }
  }
  __syncthreads();

  unsigned short* lpwB = t4g;
  unsigned short* gdXS = xs;
  for (int i = t; i < 1024; i += 256){
    int o = i >> 5, ic = i & 31;
    lpwB[o*40 + ic] = f2bu(ldin<F32>(ldw_pw_w, o*32+ic));
  }
  float gd[32];
  {
    int r = t >> 6, d = t & 63;
    #pragma unroll
    for (int oc = 0; oc < 32; oc++){
      float acc = sw[W_LDWB+oc];
      #pragma unroll
      for (int du = 0; du < 3; du++){
        #pragma unroll
        for (int dv = 0; dv < 3; dv++){
          int v2 = d + dv - 1;
          if (v2 >= 0 && v2 < 64) acc += sw[W_LDW+oc*9+du*3+dv]*u2f(xs[(oc*6+r+du)*64+v2]);
        }
      }
      gd[oc] = geluf(acc);
    }
  }
  __syncthreads();

  #pragma unroll
  for (int q = 0; q < 4; q++){
    unsigned short tmp8[8];
    #pragma unroll
    for (int j = 0; j < 8; j++) tmp8[j] = f2bu(gd[q*8+j]);
    *(short8*)&gdXS[t*40 + q*8] = *(const short8*)tmp8;
  }
  __syncthreads();

  {
    int wv = t >> 6, l = t & 63;
    int lr = l & 15, lg = l >> 4;
    #pragma unroll
    for (int mi = 0; mi < 4; mi++){
      int px0 = wv*64 + mi*16;
      short8 af = *(const short8*)&gdXS[(px0+lr)*40 + lg*8];
      #pragma unroll
      for (int ot = 0; ot < 2; ot++){
        short8 bf = *(const short8*)&lpwB[(ot*16+lr)*40 + lg*8];
        f32x4 c4 = {0.f,0.f,0.f,0.f};
        c4 = __builtin_amdgcn_mfma_f32_16x16x32_bf16(af, bf, c4, 0, 0, 0);
        int oc = ot*16 + lr;
        float bo = sw[W_LPWB+oc];
        #pragma unroll
        for (int r4 = 0; r4 < 4; r4++){
          int px = px0 + lg*4 + r4;
          int aa = a0 + (px >> 6), dd = px & 63;
          g[(size_t)n*131072 + (size_t)oc*4096 + aa*64 + dd] = f2b(c4[r4] + bo);
        }
      }
    }
  }
}

// ---------------- g-half stats2 partials ----------------
__global__ __launch_bounds__(256) void k_gstats(const bf16* __restrict__ g,
                                                float* __restrict__ partg){
  int pair = blockIdx.x >> 3, sp = blockIdx.x & 7;
  int b = pair >> 5, c = pair & 31;
  float s = 0.f, s2 = 0.f;
  for (int i = threadIdx.x; i < 32768; i += 256){
    int ii = sp*32768 + i;
    int d = ii & 63, w = (ii >> 6) & 63, h = ii >> 12;
    int n1 = h*2 + b, n2 = (63-h)*2 + b;
    float v = b2f(g[((size_t)n1*32 + c)*4096 + w*64 + d]) + b2f(g[((size_t)n2*32 + c)*4096 + w*64 + d]);
    s += v; s2 += v*v;
  }
  blk_reduce2(s, s2);
  if (threadIdx.x == 0){ partg[blockIdx.x*2] = s; partg[blockIdx.x*2+1] = s2; }
}

__global__ void k_gfinal(const float* __restrict__ partg,
                         float* __restrict__ mean2, float* __restrict__ rstd2){
  int t = threadIdx.x; if (t >= 64) return;
  float s = 0.f, s2 = 0.f;
  #pragma unroll
  for (int i = 0; i < 8; i++){ s += partg[(t*8+i)*2]; s2 += partg[(t*8+i)*2+1]; }
  float m = s * (1.f/262144.f);
  float var = s2 * (1.f/262144.f) - m*m;
  int b = t >> 5, c = t & 31;
  mean2[b*64+c] = m; rstd2[b*64+c] = rsqrtf(var + 1e-5f);
}

// ---------------- mprep ----------------
__global__ __launch_bounds__(256) void k_mprep(const int* __restrict__ flag,
    const void* __restrict__ fc1w, const void* __restrict__ fc1b,
    const void* __restrict__ fc2w, const void* __restrict__ fc2b,
    const float* __restrict__ mean2, const float* __restrict__ rstd2,
    unsigned short* __restrict__ W1p, unsigned short* __restrict__ W2b,
    float* __restrict__ b1p, float* __restrict__ b2p){
  const bool f32 = (flag[0] != 0);
  int gid = blockIdx.x*256 + threadIdx.x;
  for (int i = gid; i < 16384; i += 4096){
    int bb = i >> 13, r = i & 8191, c = r & 63;
    W1p[i] = f2bu(ldf(fc1w, r, f32) * rstd2[bb*64+c]);
  }
  for (int i = gid; i < 8192; i += 4096) W2b[i] = f2bu(ldf(fc2w, i, f32));
  if (gid < 256){
    int bb = gid >> 7, j = gid & 127;
    float s = ldf(fc1b, j, f32);
    for (int c = 0; c < 64; c++) s -= ldf(fc1w, j*64+c, f32) * mean2[bb*64+c] * rstd2[bb*64+c];
    b1p[gid] = s;
  }
  if (gid < 64) b2p[gid] = ldf(fc2b, gid, f32);
}

// ---------------- MFMA MLP (r10 proven: weights in LDS, overlays, coalesced store) ----------------
__global__ __launch_bounds__(256) void k_mlp(const int* __restrict__ flag,
    const void* __restrict__ x, const bf16* __restrict__ g,
    const unsigned short* __restrict__ W1p, const unsigned short* __restrict__ W2b,
    const float* __restrict__ b1p, const float* __restrict__ b2p,
    void* __restrict__ out){
  const bool f32 = (flag[0] != 0);
  __shared__ char smem[54272];
  unsigned short* zs  = (unsigned short*)smem;
  unsigned short* hb  = (unsigned short*)smem;
  unsigned short* w1s = (unsigned short*)(smem+18432);
  unsigned short* w2s = (unsigned short*)(smem+36864);
  float* obuf = (float*)smem;
  int blk = blockIdx.x;
  int b = blk >> 11, w = (blk >> 5) & 63, hblk = blk & 31;
  int h0 = hblk*2;
  int t = threadIdx.x;
  int wv = t >> 6, l = t & 63;
  int lr = l & 15, lg = l >> 4;

  const unsigned short* W1g = W1p + b*8192;
  for (int i = t; i < 1024; i += 256){
    int j = i >> 3, q = i & 7;
    *(short8*)&w1s[j*72 + q*8] = *(const short8*)&W1g[j*64 + q*8];
  }
  for (int i = t; i < 1024; i += 256){
    int o = i >> 4, q = i & 15;
    *(short8*)&w2s[o*136 + q*8] = *(const short8*)&W2b[o*128 + q*8];
  }
  float bj_r[8], bo_r[4];
  #pragma unroll
  for (int jt = 0; jt < 8; jt++) bj_r[jt] = b1p[b*128 + jt*16 + lr];
  #pragma unroll
  for (int ot = 0; ot < 4; ot++) bo_r[ot] = b2p[ot*16 + lr];

  {
    int px = t & 127, half = t >> 7;
    int hh = px >> 6, d = px & 63;
    int h = h0 + hh;
    unsigned short tmp[32];
    if (half == 0){
      int n1 = h*2 + b, n2 = (63-h)*2 + b;
      const bf16* g1 = g + ((size_t)n1*32)*4096 + w*64 + d;
      const bf16* g2 = g + ((size_t)n2*32)*4096 + w*64 + d;
      #pragma unroll
      for (int c = 0; c < 32; c++) tmp[c] = f2bu(b2f(g1[(size_t)c*4096]) + b2f(g2[(size_t)c*4096]));
    } else {
      size_t xi = ((size_t)(b*64+32))*SSS + (size_t)w*4096 + (size_t)h*64 + d;
      if (f32){
        const float* xp = (const float*)x;
        #pragma unroll
        for (int c = 0; c < 32; c++) tmp[c] = f2bu(xp[xi + (size_t)c*SSS]);
      } else {
        const unsigned short* xp = (const unsigned short*)x;
        #pragma unroll
        for (int c = 0; c < 32; c++) tmp[c] = xp[xi + (size_t)c*SSS];
      }
    }
    short8* dst = (short8*)&zs[px*72 + half*32];
    #pragma unroll
    for (int q = 0; q < 4; q++) dst[q] = *(short8*)&tmp[q*8];
  }
  __syncthreads();

  short8 a0f[2], a1f[2];
  #pragma unroll
  for (int mi = 0; mi < 2; mi++){
    int px0 = wv*32 + mi*16;
    a0f[mi] = *(const short8*)&zs[(px0+lr)*72 + lg*8];
    a1f[mi] = *(const short8*)&zs[(px0+lr)*72 + 32 + lg*8];
  }
  __syncthreads();

  unsigned short* hbw = &hb[wv*16*136];
  float ov[2][4][4];
  #pragma unroll
  for (int mi = 0; mi < 2; mi++){
    f32x4 acc[8];
    #pragma unroll
    for (int jt = 0; jt < 8; jt++){
      short8 b0 = *(const short8*)&w1s[(jt*16+lr)*72 + lg*8];
      short8 b1 = *(const short8*)&w1s[(jt*16+lr)*72 + 32 + lg*8];
      f32x4 c4 = {0.f,0.f,0.f,0.f};
      c4 = __builtin_amdgcn_mfma_f32_16x16x32_bf16(a0f[mi], b0, c4, 0, 0, 0);
      c4 = __builtin_amdgcn_mfma_f32_16x16x32_bf16(a1f[mi], b1, c4, 0, 0, 0);
      acc[jt] = c4;
    }
    #pragma unroll
    for (int jt = 0; jt < 8; jt++){
      float bj = bj_r[jt];
      #pragma unroll
      for (int r = 0; r < 4; r++){
        hbw[(lg*4+r)*136 + jt*16 + lr] = f2bu(geluf(acc[jt][r] + bj));
      }
    }
    short8 ha[4];
    #pragma unroll
    for (int m = 0; m < 4; m++) ha[m] = *(const short8*)&hbw[lr*136 + m*32 + lg*8];
    #pragma unroll
    for (int ot = 0; ot < 4; ot++){
      f32x4 c4 = {0.f,0.f,0.f,0.f};
      #pragma unroll
      for (int m = 0; m < 4; m++){
        short8 bb = *(const short8*)&w2s[(ot*16+lr)*136 + m*32 + lg*8];
        c4 = __builtin_amdgcn_mfma_f32_16x16x32_bf16(ha[m], bb, c4, 0, 0, 0);
      }
      #pragma unroll
      for (int r4 = 0; r4 < 4; r4++) ov[mi][ot][r4] = c4[r4];
    }
  }
  __syncthreads();

  #pragma unroll
  for (int mi = 0; mi < 2; mi++){
    int px0 = wv*32 + mi*16;
    #pragma unroll
    for (int ot = 0; ot < 4; ot++){
      float bo = bo_r[ot];
      int oc = ot*16 + lr;
      #pragma unroll
      for (int r4 = 0; r4 < 4; r4++){
        obuf[oc*129 + px0 + lg*4 + r4] = ov[mi][ot][r4] + bo;
      }
    }
  }
  __syncthreads();

  {
    int oc = t >> 2, ch = t & 3;
    size_t base = ((size_t)(b*64+oc))*SSS + (size_t)w*4096 + (size_t)h0*64 + ch*32;
    const float* src = &obuf[oc*129 + ch*32];
    if (f32){
      float* op = (float*)out;
      #pragma unroll
      for (int k = 0; k < 8; k++){
        float4 v; v.x = src[k*4]; v.y = src[k*4+1]; v.z = src[k*4+2]; v.w = src[k*4+3];
        *(float4*)&op[base + k*4] = v;
      }
    } else {
      bf16* op = (bf16*)out;
      #pragma unroll
      for (int k = 0; k < 4; k++){
        unsigned short tmp8[8];
        #pragma unroll
        for (int j = 0; j < 8; j++) tmp8[j] = f2bu(src[k*8+j]);
        *(short8*)&op[base + k*8] = *(const short8*)tmp8;
      }
    }
  }
}

extern "C" void kernel_launch(void* const* d_in, const int* in_sizes, int n_in,
                              void* d_out, int out_size, void* d_ws, size_t ws_size,
                              hipStream_t stream) {
  const void* X      = d_in[0];
  const void* n1g    = d_in[1];
  const void* n1b    = d_in[2];
  const void* n2g    = d_in[3];
  const void* n2b    = d_in[4];
  const void* p_xy   = d_in[5];
  const void* p_zx   = d_in[6];
  const void* p_zy   = d_in[7];
  const void* xy_dw_w= d_in[8];
  const void* xy_dw_b= d_in[9];
  const void* xy_pw_w= d_in[10];
  const void* xy_pw_b= d_in[11];
  const void* zx_dw_w= d_in[12];
  const void* zx_dw_b= d_in[13];
  const void* zx_pw_w= d_in[14];
  const void* zx_pw_b= d_in[15];
  const void* zy_dw_w= d_in[16];
  const void* zy_dw_b= d_in[17];
  const void* zy_pw_w= d_in[18];
  const void* zy_pw_b= d_in[19];
  const void* dw_pw_w= d_in[20];
  const void* dw_pw_b= d_in[21];
  const void* dw_dw_w= d_in[22];
  const void* dw_dw_b= d_in[23];
  const void* ldw_dw_w=d_in[24];
  const void* ldw_dw_b=d_in[25];
  const void* ldw_pw_w=d_in[26];
  const void* ldw_pw_b=d_in[27];
  const void* fc1w   = d_in[28];
  const void* fc1b   = d_in[29];
  const void* fc2w   = d_in[30];
  const void* fc2b   = d_in[31];

  int*  flag = (int*)d_ws;
  bf16* g    = (bf16*)((char*)d_ws + 16);
  float* fb  = (float*)((char*)d_ws + 16 + (size_t)16777216*2);
  float* meanH = fb;
  float* rstdH = fb + 64;
  float* t_xy  = fb + 128;
  float* t_zx  = fb + 32896;
  float* t_zy  = fb + 33408;
  float* kxy   = fb + 33920;
  float* kz    = fb + 66688;
  float* ky    = fb + 67200;
  float* mean2 = fb + 67712;
  float* rstd2 = fb + 67840;
  float* part  = fb + 67968;
  float* partg = fb + 70016;
  float* b1p   = fb + 71040;
  float* b2p   = fb + 71296;
  unsigned short* W1p = (unsigned short*)(fb + 71360);
  unsigned short* W2b = (unsigned short*)(fb + 79552);

  k_probe<<<1, 64, 0, stream>>>((const unsigned short*)X, flag);
  k_cstats<<<1024, 256, 0, stream>>>(flag, X, part);
  k_sfinal<<<1, 128, 0, stream>>>(part, meanH, rstdH, mean2, rstd2);
  k_mult1<<<132, 256, 0, stream>>>(flag, p_xy, p_zx, p_zy, xy_dw_w, xy_dw_b,
                                   zx_dw_w, zx_dw_b, zy_dw_w, zy_dw_b, t_xy, t_zx, t_zy);
  k_mult2<<<132, 256, 0, stream>>>(flag, t_xy, t_zx, t_zy, xy_pw_w, xy_pw_b,
                                   zx_pw_w, zx_pw_b, zy_pw_w, zy_pw_b, kxy, kz, ky);
  k_g<false><<<128*(64/TB), 256, 0, stream>>>(flag, X, n1g, n1b, n2g, n2b,
                                       dw_pw_w, dw_pw_b, dw_dw_w, dw_dw_b,
                                       ldw_dw_w, ldw_dw_b, ldw_pw_w, ldw_pw_b,
                                       meanH, rstdH, kxy, kz, ky, g);
  k_g<true ><<<128*(64/TB), 256, 0, stream>>>(flag, X, n1g, n1b, n2g, n2b,
                                       dw_pw_w, dw_pw_b, dw_dw_w, dw_dw_b,
                                       ldw_dw_w, ldw_dw_b, ldw_pw_w, ldw_pw_b,
                                       meanH, rstdH, kxy, kz, ky, g);
  k_gstats<<<512, 256, 0, stream>>>(g, partg);
  k_gfinal<<<1, 64, 0, stream>>>(partg, mean2, rstd2);
  k_mprep<<<16, 256, 0, stream>>>(flag, fc1w, fc1b, fc2w, fc2b, mean2, rstd2,
                                  W1p, W2b, b1p, b2p);
  k_mlp<<<4096, 256, 0, stream>>>(flag, X, g, W1p, W2b, b1p, b2p, d_out);
}

// Round 13
// 371.503 us; speedup vs baseline: 1.2735x; 1.0109x over previous
//
#include <hip/hip_runtime.h>
#include <hip/hip_bf16.h>

typedef __hip_bfloat16 bf16;
typedef __attribute__((ext_vector_type(8))) short short8;
typedef __attribute__((ext_vector_type(4))) float f32x4;

__device__ __forceinline__ float b2f(bf16 v){ return __bfloat162float(v); }
__device__ __forceinline__ bf16  f2b(float v){ return __float2bfloat16(v); }
__device__ __forceinline__ unsigned short f2bu(float f){
  return __builtin_bit_cast(unsigned short, __float2bfloat16(f));
}
__device__ __forceinline__ float u2f(unsigned short u){
  return __uint_as_float(((unsigned int)u) << 16);
}
// fast gelu: tanh form, overflow-safe. max |err| vs erf ~8e-4
__device__ __forceinline__ float geluf(float x){
  float t = 0.7978845608028654f*(x + 0.044715f*x*x*x);
  float e = __expf(2.f*t);
  float th = 1.f - 2.f/(e + 1.f);
  return 0.5f*x*(1.f + th);
}

template<bool F32> __device__ __forceinline__ float ldin(const void* p, size_t i){
  if (F32) return ((const float*)p)[i];
  return b2f(((const bf16*)p)[i]);
}
__device__ __forceinline__ float ldf(const void* p, size_t i, bool f32){
  return f32 ? ((const float*)p)[i] : b2f(((const bf16*)p)[i]);
}

#define SS    4096      // 64*64
#define SSS   262144    // 64^3

// ---------------- dtype probe ----------------
__global__ void k_probe(const unsigned short* __restrict__ xr, int* __restrict__ flag){
  float m = 0.f;
  for (int i = threadIdx.x; i < 512; i += 64){
    unsigned int u = ((unsigned int)xr[i]) << 16;
    float v = fabsf(__uint_as_float(u));
    if (!(v < 3.0e38f)) v = 3.0e38f;
    m = fmaxf(m, v);
  }
  #pragma unroll
  for (int off = 32; off > 0; off >>= 1) m = fmaxf(m, __shfl_down(m, off));
  if (threadIdx.x == 0) flag[0] = (m > 1000.0f) ? 1 : 0;
}

// ---------------- block reduction helper ----------------
__device__ __forceinline__ void blk_reduce2(float& s, float& s2){
  __shared__ float sa[4], sb[4];
  #pragma unroll
  for (int off = 32; off > 0; off >>= 1){ s += __shfl_down(s, off); s2 += __shfl_down(s2, off); }
  int wid = threadIdx.x >> 6;
  if ((threadIdx.x & 63) == 0){ sa[wid] = s; sb[wid] = s2; }
  __syncthreads();
  if (threadIdx.x == 0){ s = sa[0]+sa[1]+sa[2]+sa[3]; s2 = sb[0]+sb[1]+sb[2]+sb[3]; }
}

// ---------------- x stats ----------------
__global__ __launch_bounds__(256) void k_cstats(const int* __restrict__ flag,
    const void* __restrict__ x, float* __restrict__ part){
  const bool f32 = (flag[0] != 0);
  int bc = blockIdx.x >> 3, sp = blockIdx.x & 7;
  size_t base = (size_t)bc*SSS + (size_t)sp*32768;
  float s = 0.f, s2 = 0.f;
  if (f32){
    const float4* p = (const float4*)((const float*)x + base);
    for (int i = threadIdx.x; i < 8192; i += 256){
      float4 v = p[i];
      s += v.x+v.y+v.z+v.w; s2 += v.x*v.x+v.y*v.y+v.z*v.z+v.w*v.w;
    }
  } else {
    const ushort4* p = (const ushort4*)((const unsigned short*)x + base);
    for (int i = threadIdx.x; i < 8192; i += 256){
      ushort4 v = p[i];
      float a=u2f(v.x),b_=u2f(v.y),c=u2f(v.z),d=u2f(v.w);
      s += a+b_+c+d; s2 += a*a+b_*b_+c*c+d*d;
    }
  }
  blk_reduce2(s, s2);
  if (threadIdx.x == 0){ part[blockIdx.x*2] = s; part[blockIdx.x*2+1] = s2; }
}

__global__ void k_sfinal(const float* __restrict__ part,
    float* __restrict__ meanH, float* __restrict__ rstdH,
    float* __restrict__ mean2, float* __restrict__ rstd2){
  int t = threadIdx.x; if (t >= 128) return;
  float s = 0.f, s2 = 0.f;
  #pragma unroll
  for (int i = 0; i < 8; i++){ s += part[(t*8+i)*2]; s2 += part[(t*8+i)*2+1]; }
  float m = s * (1.f/262144.f);
  float var = s2 * (1.f/262144.f) - m*m;
  int b = t >> 6, c = t & 63;
  if (c < 32){ meanH[b*32+c] = m; rstdH[b*32+c] = rsqrtf(var + 1e-5f); }
  else       { mean2[t] = m;      rstd2[t] = rsqrtf(var + 1e-5f); }
}

// ---------------- multiplier chain stage 1 ----------------
__global__ __launch_bounds__(256) void k_mult1(const int* __restrict__ flag,
    const void* __restrict__ p_xy, const void* __restrict__ p_zx, const void* __restrict__ p_zy,
    const void* __restrict__ xy_dw_w, const void* __restrict__ xy_dw_b,
    const void* __restrict__ zx_dw_w, const void* __restrict__ zx_dw_b,
    const void* __restrict__ zy_dw_w, const void* __restrict__ zy_dw_b,
    float* __restrict__ t_xy, float* __restrict__ t_zx, float* __restrict__ t_zy){
  const bool f32 = (flag[0] != 0);
  const float SC = 31.f/63.f;
  int id = blockIdx.x*256 + threadIdx.x;
  if (id < 32768){
    int c = id >> 12, rem = id & 4095, uu = rem >> 6, vv = rem & 63;
    float acc = ldf(xy_dw_b, c, f32);
    for (int du = 0; du < 3; du++){
      int ui = uu + du - 1; if (ui < 0 || ui >= 64) continue;
      float pu = ui*SC; int i0 = (int)pu; float wu = pu - (float)i0; int i1 = min(i0+1, 31);
      for (int dv = 0; dv < 3; dv++){
        int vi = vv + dv - 1; if (vi < 0 || vi >= 64) continue;
        float pv = vi*SC; int j0 = (int)pv; float wv = pv - (float)j0; int j1 = min(j0+1, 31);
        float s = ldf(p_xy, c*1024+i0*32+j0, f32)*(1.f-wu)*(1.f-wv) + ldf(p_xy, c*1024+i0*32+j1, f32)*(1.f-wu)*wv
                + ldf(p_xy, c*1024+i1*32+j0, f32)*wu*(1.f-wv)       + ldf(p_xy, c*1024+i1*32+j1, f32)*wu*wv;
        acc += ldf(xy_dw_w, c*9 + du*3 + dv, f32) * s;
      }
    }
    t_xy[id] = geluf(acc);
  } else if (id < 33280){
    int k = id - 32768; int c = k >> 6, a = k & 63;
    float acc = ldf(zx_dw_b, c, f32);
    for (int da = 0; da < 3; da++){
      int ai = a + da - 1; if (ai < 0 || ai >= 64) continue;
      float pa = ai*SC; int i0 = (int)pa; float wa = pa - (float)i0; int i1 = min(i0+1, 31);
      float s = ldf(p_zx, c*32+i0, f32)*(1.f-wa) + ldf(p_zx, c*32+i1, f32)*wa;
      acc += ldf(zx_dw_w, c*3+da, f32) * s;
    }
    t_zx[k] = geluf(acc);
  } else if (id < 33792){
    int k = id - 33280; int c = k >> 6, a = k & 63;
    float acc = ldf(zy_dw_b, c, f32);
    for (int da = 0; da < 3; da++){
      int ai = a + da - 1; if (ai < 0 || ai >= 64) continue;
      float pa = ai*SC; int i0 = (int)pa; float wa = pa - (float)i0; int i1 = min(i0+1, 31);
      float s = ldf(p_zy, c*32+i0, f32)*(1.f-wa) + ldf(p_zy, c*32+i1, f32)*wa;
      acc += ldf(zy_dw_w, c*3+da, f32) * s;
    }
    t_zy[k] = geluf(acc);
  }
}

// ---------------- multiplier chain stage 2 ----------------
__global__ __launch_bounds__(256) void k_mult2(const int* __restrict__ flag,
    const float* __restrict__ t_xy, const float* __restrict__ t_zx, const float* __restrict__ t_zy,
    const void* __restrict__ xy_pw_w, const void* __restrict__ xy_pw_b,
    const void* __restrict__ zx_pw_w, const void* __restrict__ zx_pw_b,
    const void* __restrict__ zy_pw_w, const void* __restrict__ zy_pw_b,
    float* __restrict__ kxy, float* __restrict__ kz, float* __restrict__ ky){
  const bool f32 = (flag[0] != 0);
  int id = blockIdx.x*256 + threadIdx.x;
  if (id < 32768){
    int oc = id >> 12, pix = id & 4095;
    float acc = ldf(xy_pw_b, oc, f32);
    #pragma unroll
    for (int ic = 0; ic < 8; ic++) acc += ldf(xy_pw_w, oc*8+ic, f32) * t_xy[ic*4096 + pix];
    kxy[id] = acc;
  } else if (id < 33280){
    int k = id - 32768; int oc = k >> 6, a = k & 63;
    float acc = ldf(zx_pw_b, oc, f32);
    #pragma unroll
    for (int ic = 0; ic < 8; ic++) acc += ldf(zx_pw_w, oc*8+ic, f32) * t_zx[ic*64 + a];
    kz[k] = acc;
  } else if (id < 33792){
    int k = id - 33280; int oc = k >> 6, a = k & 63;
    float acc = ldf(zy_pw_b, oc, f32);
    #pragma unroll
    for (int ic = 0; ic < 8; ic++) acc += ldf(zy_pw_w, oc*8+ic, f32) * t_zy[ic*64 + a];
    ky[k] = acc;
  }
}

// ---------------- fused G: TB=8, 512 threads, scalar per-thread structure (r10 bodies) ----------------
// LDS: xs[32][10][64] 40KB + t4g[8][12][64] 12KB + muinv 5KB + sw 2.8KB ~= 60KB -> 2 blocks/CU x 8 waves.
#define TB 8
#define W_M    0
#define W_R    32
#define W_G1   64
#define W_B1   96
#define W_G2   128
#define W_B2   160
#define W_LDWB 192
#define W_LPWB 224
#define W_PW   256
#define W_PWB  320
#define W_DW   328
#define W_DWB  400
#define W_LDW  408
#define W_TOT  696

template<bool F32>
__global__ __launch_bounds__(512) void k_g(const int* __restrict__ flag,
    const void* __restrict__ x,
    const void* n1g_, const void* n1b_, const void* n2g_, const void* n2b_,
    const void* dwpw_w, const void* dwpw_b, const void* dwdw_w, const void* dwdw_b,
    const void* ldw_dw_w, const void* ldw_dw_b, const void* ldw_pw_w, const void* ldw_pw_b,
    const float* __restrict__ meanH, const float* __restrict__ rstdH,
    const float* __restrict__ kxy, const float* __restrict__ kz, const float* __restrict__ ky,
    bf16* __restrict__ g){
  if (flag[0] != (F32 ? 1 : 0)) return;
  __shared__ unsigned short xs[32*10*64];   // [c][rx10][64]; later gdbuf [512][40]
  __shared__ unsigned short t4g[8*12*64];   // [ic][rt12][64]; later lpwB [32][40]
  __shared__ float muinv[2*10*64];          // mu [0..639], inv [640..1279]
  __shared__ float sw[W_TOT];
  int n  = blockIdx.x >> 3;            // 8 tiles of TB=8 rows
  int a0 = (blockIdx.x & 7) * TB;
  int b = n & 1, h = n >> 1;
  int t = threadIdx.x;
  if (t < 32){
    sw[W_M+t]=meanH[b*32+t]; sw[W_R+t]=rstdH[b*32+t];
    sw[W_G1+t]=ldin<F32>(n1g_, t); sw[W_B1+t]=ldin<F32>(n1b_, t);
    sw[W_G2+t]=ldin<F32>(n2g_, t); sw[W_B2+t]=ldin<F32>(n2b_, t);
    sw[W_LDWB+t]=ldin<F32>(ldw_dw_b, t); sw[W_LPWB+t]=ldin<F32>(ldw_pw_b, t);
  }
  if (t >= 64 && t < 128) sw[W_PW+t-64]=ldin<F32>(dwpw_w, t-64);
  if (t >= 128 && t < 200) sw[W_DW+t-128]=ldin<F32>(dwdw_w, t-128);
  if (t >= 200 && t < 208) sw[W_PWB+t-200]=ldin<F32>(dwpw_b, t-200);
  if (t >= 208 && t < 216) sw[W_DWB+t-208]=ldin<F32>(dwdw_b, t-208);
  if (t >= 224 && t < 512){ int i = t - 224; sw[W_LDW+i] = ldin<F32>(ldw_dw_w, i); }
  __syncthreads();
  const float* s_g1 = sw+W_G1; const float* s_b1 = sw+W_B1;
  const float* s_g2 = sw+W_G2; const float* s_b2 = sw+W_B2;
  const size_t xbase = (size_t)b*64*SSS + (size_t)h*64;

  // stage xs rows a0-1 .. a0+8 (10 rows) = normalized x (vectorized, coalesced)
  for (int i = t; i < 5120; i += 512){
    int c = i / 160, rem = i - c*160, row = rem >> 4, q = rem & 15;
    int a = a0 - 1 + row;
    unsigned short o0=0,o1=0,o2=0,o3=0;
    if (a >= 0 && a < 64){
      float m = sw[W_M+c], r = sw[W_R+c];
      size_t base = xbase + (size_t)c*SSS + (size_t)a*SS + q*4;
      if (F32){
        float4 v = *(const float4*)((const float*)x + base);
        o0=f2bu((v.x-m)*r); o1=f2bu((v.y-m)*r); o2=f2bu((v.z-m)*r); o3=f2bu((v.w-m)*r);
      } else {
        ushort4 v = *(const ushort4*)((const unsigned short*)x + base);
        o0=f2bu((u2f(v.x)-m)*r); o1=f2bu((u2f(v.y)-m)*r); o2=f2bu((u2f(v.z)-m)*r); o3=f2bu((u2f(v.w)-m)*r);
      }
    }
    ushort4 o4; o4.x=o0; o4.y=o1; o4.z=o2; o4.w=o3;
    *(ushort4*)&xs[(c*10+row)*64 + q*4] = o4;
  }
  __syncthreads();

  // phase 1: t4g for 12 rows (a0-2 .. a0+9). Rows 1..10 from xs (cache mu/inv); rows 0,11 streamed.
  for (int p = t; p < 12*64; p += 512){
    int row = p >> 6, d = p & 63;
    int a = a0 - 2 + row;
    if (a < 0 || a >= 64){
      #pragma unroll
      for (int ic = 0; ic < 8; ic++) t4g[(ic*12+row)*64+d] = 0;
      continue;
    }
    float sum = 0.f, sq = 0.f; float z24[8];
    if (row >= 1 && row <= 10){
      int r10_ = row - 1;
      #pragma unroll
      for (int c = 0; c < 32; c++){
        float v = u2f(xs[(c*10+r10_)*64+d]); sum += v; sq += v*v;
        if (c >= 24) z24[c-24] = v;
      }
    } else {
      size_t xi = xbase + (size_t)a*SS + d;
      #pragma unroll
      for (int c = 0; c < 32; c++){
        float v = (ldin<F32>(x, xi + (size_t)c*SSS) - sw[W_M+c]) * sw[W_R+c];
        sum += v; sq += v*v;
        if (c >= 24) z24[c-24] = v;
      }
    }
    float mu = sum * (1.f/32.f);
    float inv = rsqrtf(sq*(1.f/32.f) - mu*mu + 1e-6f);
    if (row >= 1 && row <= 10){
      muinv[(row-1)*64+d] = mu; muinv[640 + (row-1)*64+d] = inv;
    }
    float zl[8];
    #pragma unroll
    for (int j = 0; j < 8; j++) zl[j] = (z24[j]-mu)*inv*s_g1[24+j] + s_b1[24+j];
    #pragma unroll
    for (int ic = 0; ic < 8; ic++){
      float acc = sw[W_PWB+ic];
      #pragma unroll
      for (int j = 0; j < 8; j++) acc += sw[W_PW+ic*8+j]*zl[j];
      t4g[(ic*12+row)*64+d] = f2bu(geluf(acc));
    }
  }
  __syncthreads();

  // phase 2: in-place transform of xs rows 0..9 (a = a0-1 .. a0+8)
  for (int p = t; p < 10*64; p += 512){
    int r2 = p >> 6, d = p & 63;
    int a = a0 - 1 + r2;
    if (a < 0 || a >= 64) continue;
    float mu = muinv[r2*64+d], inv = muinv[640 + r2*64+d];
    float s2 = 0.f, q2 = 0.f;
    #pragma unroll
    for (int c = 0; c < 8; c++){
      int idx = (c*10+r2)*64+d;
      float u = ((u2f(xs[idx])-mu)*inv*s_g1[c] + s_b1[c]) * kxy[(c*64 + a)*64 + d];
      xs[idx] = f2bu(u); s2 += u; q2 += u*u;
    }
    #pragma unroll
    for (int c = 8; c < 16; c++){
      int idx = (c*10+r2)*64+d;
      float u = ((u2f(xs[idx])-mu)*inv*s_g1[c] + s_b1[c]) * kz[(c-8)*64 + a];
      xs[idx] = f2bu(u); s2 += u; q2 += u*u;
    }
    #pragma unroll
    for (int c = 16; c < 24; c++){
      int idx = (c*10+r2)*64+d;
      float u = ((u2f(xs[idx])-mu)*inv*s_g1[c] + s_b1[c]) * ky[(c-16)*64 + d];
      xs[idx] = f2bu(u); s2 += u; q2 += u*u;
    }
    #pragma unroll
    for (int oc = 0; oc < 8; oc++){
      float acc = sw[W_DWB+oc];
      #pragma unroll
      for (int du = 0; du < 3; du++){
        #pragma unroll
        for (int dv = 0; dv < 3; dv++){
          int v2 = d + dv - 1;
          if (v2 >= 0 && v2 < 64) acc += sw[W_DW+oc*9+du*3+dv]*u2f(t4g[(oc*12+r2+du)*64+v2]);
        }
      }
      xs[((24+oc)*10+r2)*64+d] = f2bu(acc); s2 += acc; q2 += acc*acc;
    }
    float mu2 = s2 * (1.f/32.f);
    float inv2 = rsqrtf(q2*(1.f/32.f) - mu2*mu2 + 1e-6f);
    #pragma unroll
    for (int c = 0; c < 32; c++){
      int idx = (c*10+r2)*64+d;
      float uu = u2f(xs[idx]);
      xs[idx] = f2bu((uu-mu2)*inv2*s_g2[c] + s_b2[c]);
    }
  }
  __syncthreads();

  // phase 3a: stage lpw bf16 into t4g region; ldw dw3x3 + gelu -> regs
  unsigned short* lpwB = t4g;
  unsigned short* gdXS = xs;
  for (int i = t; i < 1024; i += 512){
    int o = i >> 5, ic = i & 31;
    lpwB[o*40 + ic] = f2bu(ldin<F32>(ldw_pw_w, o*32+ic));
  }
  float gd[32];
  {
    int r = t >> 6, d = t & 63;     // output row a0+r (r in 0..7), xs tap rows r..r+2
    #pragma unroll
    for (int oc = 0; oc < 32; oc++){
      float acc = sw[W_LDWB+oc];
      #pragma unroll
      for (int du = 0; du < 3; du++){
        #pragma unroll
        for (int dv = 0; dv < 3; dv++){
          int v2 = d + dv - 1;
          if (v2 >= 0 && v2 < 64) acc += sw[W_LDW+oc*9+du*3+dv]*u2f(xs[(oc*10+r+du)*64+v2]);
        }
      }
      gd[oc] = geluf(acc);
    }
  }
  __syncthreads();     // all xs conv reads + lpwB writes done

  // write gelu(gd) bf16 over xs region: gdbuf[512][40]
  #pragma unroll
  for (int q = 0; q < 4; q++){
    unsigned short tmp8[8];
    #pragma unroll
    for (int j = 0; j < 8; j++) tmp8[j] = f2bu(gd[q*8+j]);
    *(short8*)&gdXS[t*40 + q*8] = *(const short8*)tmp8;
  }
  __syncthreads();

  // phase 3b: MFMA pointwise 512px x 32oc, K=32 (8 waves x 64px each)
  {
    int wv = t >> 6, l = t & 63;
    int lr = l & 15, lg = l >> 4;
    #pragma unroll
    for (int mi = 0; mi < 4; mi++){
      int px0 = wv*64 + mi*16;
      short8 af = *(const short8*)&gdXS[(px0+lr)*40 + lg*8];
      #pragma unroll
      for (int ot = 0; ot < 2; ot++){
        short8 bf = *(const short8*)&lpwB[(ot*16+lr)*40 + lg*8];
        f32x4 c4 = {0.f,0.f,0.f,0.f};
        c4 = __builtin_amdgcn_mfma_f32_16x16x32_bf16(af, bf, c4, 0, 0, 0);
        int oc = ot*16 + lr;
        float bo = sw[W_LPWB+oc];
        #pragma unroll
        for (int r4 = 0; r4 < 4; r4++){
          int px = px0 + lg*4 + r4;
          int aa = a0 + (px >> 6), dd = px & 63;
          g[(size_t)n*131072 + (size_t)oc*4096 + aa*64 + dd] = f2b(c4[r4] + bo);
        }
      }
    }
  }
}

// ---------------- g-half stats2 partials ----------------
__global__ __launch_bounds__(256) void k_gstats(const bf16* __restrict__ g,
                                                float* __restrict__ partg){
  int pair = blockIdx.x >> 3, sp = blockIdx.x & 7;
  int b = pair >> 5, c = pair & 31;
  float s = 0.f, s2 = 0.f;
  for (int i = threadIdx.x; i < 32768; i += 256){
    int ii = sp*32768 + i;
    int d = ii & 63, w = (ii >> 6) & 63, h = ii >> 12;
    int n1 = h*2 + b, n2 = (63-h)*2 + b;
    float v = b2f(g[((size_t)n1*32 + c)*4096 + w*64 + d]) + b2f(g[((size_t)n2*32 + c)*4096 + w*64 + d]);
    s += v; s2 += v*v;
  }
  blk_reduce2(s, s2);
  if (threadIdx.x == 0){ partg[blockIdx.x*2] = s; partg[blockIdx.x*2+1] = s2; }
}

__global__ void k_gfinal(const float* __restrict__ partg,
                         float* __restrict__ mean2, float* __restrict__ rstd2){
  int t = threadIdx.x; if (t >= 64) return;
  float s = 0.f, s2 = 0.f;
  #pragma unroll
  for (int i = 0; i < 8; i++){ s += partg[(t*8+i)*2]; s2 += partg[(t*8+i)*2+1]; }
  float m = s * (1.f/262144.f);
  float var = s2 * (1.f/262144.f) - m*m;
  int b = t >> 5, c = t & 31;
  mean2[b*64+c] = m; rstd2[b*64+c] = rsqrtf(var + 1e-5f);
}

// ---------------- mprep ----------------
__global__ __launch_bounds__(256) void k_mprep(const int* __restrict__ flag,
    const void* __restrict__ fc1w, const void* __restrict__ fc1b,
    const void* __restrict__ fc2w, const void* __restrict__ fc2b,
    const float* __restrict__ mean2, const float* __restrict__ rstd2,
    unsigned short* __restrict__ W1p, unsigned short* __restrict__ W2b,
    float* __restrict__ b1p, float* __restrict__ b2p){
  const bool f32 = (flag[0] != 0);
  int gid = blockIdx.x*256 + threadIdx.x;
  for (int i = gid; i < 16384; i += 4096){
    int bb = i >> 13, r = i & 8191, c = r & 63;
    W1p[i] = f2bu(ldf(fc1w, r, f32) * rstd2[bb*64+c]);
  }
  for (int i = gid; i < 8192; i += 4096) W2b[i] = f2bu(ldf(fc2w, i, f32));
  if (gid < 256){
    int bb = gid >> 7, j = gid & 127;
    float s = ldf(fc1b, j, f32);
    for (int c = 0; c < 64; c++) s -= ldf(fc1w, j*64+c, f32) * mean2[bb*64+c] * rstd2[bb*64+c];
    b1p[gid] = s;
  }
  if (gid < 64) b2p[gid] = ldf(fc2b, gid, f32);
}

// ---------------- MFMA MLP (r10 proven) ----------------
__global__ __launch_bounds__(256) void k_mlp(const int* __restrict__ flag,
    const void* __restrict__ x, const bf16* __restrict__ g,
    const unsigned short* __restrict__ W1p, const unsigned short* __restrict__ W2b,
    const float* __restrict__ b1p, const float* __restrict__ b2p,
    void* __restrict__ out){
  const bool f32 = (flag[0] != 0);
  __shared__ char smem[54272];
  unsigned short* zs  = (unsigned short*)smem;
  unsigned short* hb  = (unsigned short*)smem;
  unsigned short* w1s = (unsigned short*)(smem+18432);
  unsigned short* w2s = (unsigned short*)(smem+36864);
  float* obuf = (float*)smem;
  int blk = blockIdx.x;
  int b = blk >> 11, w = (blk >> 5) & 63, hblk = blk & 31;
  int h0 = hblk*2;
  int t = threadIdx.x;
  int wv = t >> 6, l = t & 63;
  int lr = l & 15, lg = l >> 4;

  const unsigned short* W1g = W1p + b*8192;
  for (int i = t; i < 1024; i += 256){
    int j = i >> 3, q = i & 7;
    *(short8*)&w1s[j*72 + q*8] = *(const short8*)&W1g[j*64 + q*8];
  }
  for (int i = t; i < 1024; i += 256){
    int o = i >> 4, q = i & 15;
    *(short8*)&w2s[o*136 + q*8] = *(const short8*)&W2b[o*128 + q*8];
  }
  float bj_r[8], bo_r[4];
  #pragma unroll
  for (int jt = 0; jt < 8; jt++) bj_r[jt] = b1p[b*128 + jt*16 + lr];
  #pragma unroll
  for (int ot = 0; ot < 4; ot++) bo_r[ot] = b2p[ot*16 + lr];

  {
    int px = t & 127, half = t >> 7;
    int hh = px >> 6, d = px & 63;
    int h = h0 + hh;
    unsigned short tmp[32];
    if (half == 0){
      int n1 = h*2 + b, n2 = (63-h)*2 + b;
      const bf16* g1 = g + ((size_t)n1*32)*4096 + w*64 + d;
      const bf16* g2 = g + ((size_t)n2*32)*4096 + w*64 + d;
      #pragma unroll
      for (int c = 0; c < 32; c++) tmp[c] = f2bu(b2f(g1[(size_t)c*4096]) + b2f(g2[(size_t)c*4096]));
    } else {
      size_t xi = ((size_t)(b*64+32))*SSS + (size_t)w*4096 + (size_t)h*64 + d;
      if (f32){
        const float* xp = (const float*)x;
        #pragma unroll
        for (int c = 0; c < 32; c++) tmp[c] = f2bu(xp[xi + (size_t)c*SSS]);
      } else {
        const unsigned short* xp = (const unsigned short*)x;
        #pragma unroll
        for (int c = 0; c < 32; c++) tmp[c] = xp[xi + (size_t)c*SSS];
      }
    }
    short8* dst = (short8*)&zs[px*72 + half*32];
    #pragma unroll
    for (int q = 0; q < 4; q++) dst[q] = *(short8*)&tmp[q*8];
  }
  __syncthreads();

  short8 a0f[2], a1f[2];
  #pragma unroll
  for (int mi = 0; mi < 2; mi++){
    int px0 = wv*32 + mi*16;
    a0f[mi] = *(const short8*)&zs[(px0+lr)*72 + lg*8];
    a1f[mi] = *(const short8*)&zs[(px0+lr)*72 + 32 + lg*8];
  }
  __syncthreads();

  unsigned short* hbw = &hb[wv*16*136];
  float ov[2][4][4];
  #pragma unroll
  for (int mi = 0; mi < 2; mi++){
    f32x4 acc[8];
    #pragma unroll
    for (int jt = 0; jt < 8; jt++){
      short8 b0 = *(const short8*)&w1s[(jt*16+lr)*72 + lg*8];
      short8 b1 = *(const short8*)&w1s[(jt*16+lr)*72 + 32 + lg*8];
      f32x4 c4 = {0.f,0.f,0.f,0.f};
      c4 = __builtin_amdgcn_mfma_f32_16x16x32_bf16(a0f[mi], b0, c4, 0, 0, 0);
      c4 = __builtin_amdgcn_mfma_f32_16x16x32_bf16(a1f[mi], b1, c4, 0, 0, 0);
      acc[jt] = c4;
    }
    #pragma unroll
    for (int jt = 0; jt < 8; jt++){
      float bj = bj_r[jt];
      #pragma unroll
      for (int r = 0; r < 4; r++){
        hbw[(lg*4+r)*136 + jt*16 + lr] = f2bu(geluf(acc[jt][r] + bj));
      }
    }
    short8 ha[4];
    #pragma unroll
    for (int m = 0; m < 4; m++) ha[m] = *(const short8*)&hbw[lr*136 + m*32 + lg*8];
    #pragma unroll
    for (int ot = 0; ot < 4; ot++){
      f32x4 c4 = {0.f,0.f,0.f,0.f};
      #pragma unroll
      for (int m = 0; m < 4; m++){
        short8 bb = *(const short8*)&w2s[(ot*16+lr)*136 + m*32 + lg*8];
        c4 = __builtin_amdgcn_mfma_f32_16x16x32_bf16(ha[m], bb, c4, 0, 0, 0);
      }
      #pragma unroll
      for (int r4 = 0; r4 < 4; r4++) ov[mi][ot][r4] = c4[r4];
    }
  }
  __syncthreads();

  #pragma unroll
  for (int mi = 0; mi < 2; mi++){
    int px0 = wv*32 + mi*16;
    #pragma unroll
    for (int ot = 0; ot < 4; ot++){
      float bo = bo_r[ot];
      int oc = ot*16 + lr;
      #pragma unroll
      for (int r4 = 0; r4 < 4; r4++){
        obuf[oc*129 + px0 + lg*4 + r4] = ov[mi][ot][r4] + bo;
      }
    }
  }
  __syncthreads();

  {
    int oc = t >> 2, ch = t & 3;
    size_t base = ((size_t)(b*64+oc))*SSS + (size_t)w*4096 + (size_t)h0*64 + ch*32;
    const float* src = &obuf[oc*129 + ch*32];
    if (f32){
      float* op = (float*)out;
      #pragma unroll
      for (int k = 0; k < 8; k++){
        float4 v; v.x = src[k*4]; v.y = src[k*4+1]; v.z = src[k*4+2]; v.w = src[k*4+3];
        *(float4*)&op[base + k*4] = v;
      }
    } else {
      bf16* op = (bf16*)out;
      #pragma unroll
      for (int k = 0; k < 4; k++){
        unsigned short tmp8[8];
        #pragma unroll
        for (int j = 0; j < 8; j++) tmp8[j] = f2bu(src[k*8+j]);
        *(short8*)&op[base + k*8] = *(const short8*)tmp8;
      }
    }
  }
}

extern "C" void kernel_launch(void* const* d_in, const int* in_sizes, int n_in,
                              void* d_out, int out_size, void* d_ws, size_t ws_size,
                              hipStream_t stream) {
  const void* X      = d_in[0];
  const void* n1g    = d_in[1];
  const void* n1b    = d_in[2];
  const void* n2g    = d_in[3];
  const void* n2b    = d_in[4];
  const void* p_xy   = d_in[5];
  const void* p_zx   = d_in[6];
  const void* p_zy   = d_in[7];
  const void* xy_dw_w= d_in[8];
  const void* xy_dw_b= d_in[9];
  const void* xy_pw_w= d_in[10];
  const void* xy_pw_b= d_in[11];
  const void* zx_dw_w= d_in[12];
  const void* zx_dw_b= d_in[13];
  const void* zx_pw_w= d_in[14];
  const void* zx_pw_b= d_in[15];
  const void* zy_dw_w= d_in[16];
  const void* zy_dw_b= d_in[17];
  const void* zy_pw_w= d_in[18];
  const void* zy_pw_b= d_in[19];
  const void* dw_pw_w= d_in[20];
  const void* dw_pw_b= d_in[21];
  const void* dw_dw_w= d_in[22];
  const void* dw_dw_b= d_in[23];
  const void* ldw_dw_w=d_in[24];
  const void* ldw_dw_b=d_in[25];
  const void* ldw_pw_w=d_in[26];
  const void* ldw_pw_b=d_in[27];
  const void* fc1w   = d_in[28];
  const void* fc1b   = d_in[29];
  const void* fc2w   = d_in[30];
  const void* fc2b   = d_in[31];

  int*  flag = (int*)d_ws;
  bf16* g    = (bf16*)((char*)d_ws + 16);
  float* fb  = (float*)((char*)d_ws + 16 + (size_t)16777216*2);
  float* meanH = fb;
  float* rstdH = fb + 64;
  float* t_xy  = fb + 128;
  float* t_zx  = fb + 32896;
  float* t_zy  = fb + 33408;
  float* kxy   = fb + 33920;
  float* kz    = fb + 66688;
  float* ky    = fb + 67200;
  float* mean2 = fb + 67712;
  float* rstd2 = fb + 67840;
  float* part  = fb + 67968;
  float* partg = fb + 70016;
  float* b1p   = fb + 71040;
  float* b2p   = fb + 71296;
  unsigned short* W1p = (unsigned short*)(fb + 71360);
  unsigned short* W2b = (unsigned short*)(fb + 79552);

  k_probe<<<1, 64, 0, stream>>>((const unsigned short*)X, flag);
  k_cstats<<<1024, 256, 0, stream>>>(flag, X, part);
  k_sfinal<<<1, 128, 0, stream>>>(part, meanH, rstdH, mean2, rstd2);
  k_mult1<<<132, 256, 0, stream>>>(flag, p_xy, p_zx, p_zy, xy_dw_w, xy_dw_b,
                                   zx_dw_w, zx_dw_b, zy_dw_w, zy_dw_b, t_xy, t_zx, t_zy);
  k_mult2<<<132, 256, 0, stream>>>(flag, t_xy, t_zx, t_zy, xy_pw_w, xy_pw_b,
                                   zx_pw_w, zx_pw_b, zy_pw_w, zy_pw_b, kxy, kz, ky);
  k_g<false><<<128*(64/TB), 512, 0, stream>>>(flag, X, n1g, n1b, n2g, n2b,
                                       dw_pw_w, dw_pw_b, dw_dw_w, dw_dw_b,
                                       ldw_dw_w, ldw_dw_b, ldw_pw_w, ldw_pw_b,
                                       meanH, rstdH, kxy, kz, ky, g);
  k_g<true ><<<128*(64/TB), 512, 0, stream>>>(flag, X, n1g, n1b, n2g, n2b,
                                       dw_pw_w, dw_pw_b, dw_dw_w, dw_dw_b,
                                       ldw_dw_w, ldw_dw_b, ldw_pw_w, ldw_pw_b,
                                       meanH, rstdH, kxy, kz, ky, g);
  k_gstats<<<512, 256, 0, stream>>>(g, partg);
  k_gfinal<<<1, 64, 0, stream>>>(partg, mean2, rstd2);
  k_mprep<<<16, 256, 0, stream>>>(flag, fc1w, fc1b, fc2w, fc2b, mean2, rstd2,
                                  W1p, W2b, b1p, b2p);
  k_mlp<<<4096, 256, 0, stream>>>(flag, X, g, W1p, W2b, b1p, b2p, d_out);
}

// Round 14
// 370.600 us; speedup vs baseline: 1.2766x; 1.0024x over previous
//
#include <hip/hip_runtime.h>
#include <hip/hip_bf16.h>

typedef __hip_bfloat16 bf16;
typedef __attribute__((ext_vector_type(8))) short short8;
typedef __attribute__((ext_vector_type(4))) float f32x4;

__device__ __forceinline__ float b2f(bf16 v){ return __bfloat162float(v); }
__device__ __forceinline__ bf16  f2b(float v){ return __float2bfloat16(v); }
__device__ __forceinline__ unsigned short f2bu(float f){
  return __builtin_bit_cast(unsigned short, __float2bfloat16(f));
}
__device__ __forceinline__ float u2f(unsigned short u){
  return __uint_as_float(((unsigned int)u) << 16);
}
// fast gelu: tanh form, overflow-safe. max |err| vs erf ~8e-4
__device__ __forceinline__ float geluf(float x){
  float t = 0.7978845608028654f*(x + 0.044715f*x*x*x);
  float e = __expf(2.f*t);
  float th = 1.f - 2.f/(e + 1.f);
  return 0.5f*x*(1.f + th);
}

template<bool F32> __device__ __forceinline__ float ldin(const void* p, size_t i){
  if (F32) return ((const float*)p)[i];
  return b2f(((const bf16*)p)[i]);
}
__device__ __forceinline__ float ldf(const void* p, size_t i, bool f32){
  return f32 ? ((const float*)p)[i] : b2f(((const bf16*)p)[i]);
}

#define SS    4096      // 64*64
#define SSS   262144    // 64^3

// ---------------- dtype probe ----------------
__global__ void k_probe(const unsigned short* __restrict__ xr, int* __restrict__ flag){
  float m = 0.f;
  for (int i = threadIdx.x; i < 512; i += 64){
    unsigned int u = ((unsigned int)xr[i]) << 16;
    float v = fabsf(__uint_as_float(u));
    if (!(v < 3.0e38f)) v = 3.0e38f;
    m = fmaxf(m, v);
  }
  #pragma unroll
  for (int off = 32; off > 0; off >>= 1) m = fmaxf(m, __shfl_down(m, off));
  if (threadIdx.x == 0) flag[0] = (m > 1000.0f) ? 1 : 0;
}

// ---------------- block reduction helper ----------------
__device__ __forceinline__ void blk_reduce2(float& s, float& s2){
  __shared__ float sa[4], sb[4];
  #pragma unroll
  for (int off = 32; off > 0; off >>= 1){ s += __shfl_down(s, off); s2 += __shfl_down(s2, off); }
  int wid = threadIdx.x >> 6;
  if ((threadIdx.x & 63) == 0){ sa[wid] = s; sb[wid] = s2; }
  __syncthreads();
  if (threadIdx.x == 0){ s = sa[0]+sa[1]+sa[2]+sa[3]; s2 = sb[0]+sb[1]+sb[2]+sb[3]; }
}

// ---------------- x stats ----------------
__global__ __launch_bounds__(256) void k_cstats(const int* __restrict__ flag,
    const void* __restrict__ x, float* __restrict__ part){
  const bool f32 = (flag[0] != 0);
  int bc = blockIdx.x >> 3, sp = blockIdx.x & 7;
  size_t base = (size_t)bc*SSS + (size_t)sp*32768;
  float s = 0.f, s2 = 0.f;
  if (f32){
    const float4* p = (const float4*)((const float*)x + base);
    for (int i = threadIdx.x; i < 8192; i += 256){
      float4 v = p[i];
      s += v.x+v.y+v.z+v.w; s2 += v.x*v.x+v.y*v.y+v.z*v.z+v.w*v.w;
    }
  } else {
    const ushort4* p = (const ushort4*)((const unsigned short*)x + base);
    for (int i = threadIdx.x; i < 8192; i += 256){
      ushort4 v = p[i];
      float a=u2f(v.x),b_=u2f(v.y),c=u2f(v.z),d=u2f(v.w);
      s += a+b_+c+d; s2 += a*a+b_*b_+c*c+d*d;
    }
  }
  blk_reduce2(s, s2);
  if (threadIdx.x == 0){ part[blockIdx.x*2] = s; part[blockIdx.x*2+1] = s2; }
}

__global__ void k_sfinal(const float* __restrict__ part,
    float* __restrict__ meanH, float* __restrict__ rstdH,
    float* __restrict__ mean2, float* __restrict__ rstd2){
  int t = threadIdx.x; if (t >= 128) return;
  float s = 0.f, s2 = 0.f;
  #pragma unroll
  for (int i = 0; i < 8; i++){ s += part[(t*8+i)*2]; s2 += part[(t*8+i)*2+1]; }
  float m = s * (1.f/262144.f);
  float var = s2 * (1.f/262144.f) - m*m;
  int b = t >> 6, c = t & 63;
  if (c < 32){ meanH[b*32+c] = m; rstdH[b*32+c] = rsqrtf(var + 1e-5f); }
  else       { mean2[t] = m;      rstd2[t] = rsqrtf(var + 1e-5f); }
}

// ---------------- multiplier chain stage 1 ----------------
__global__ __launch_bounds__(256) void k_mult1(const int* __restrict__ flag,
    const void* __restrict__ p_xy, const void* __restrict__ p_zx, const void* __restrict__ p_zy,
    const void* __restrict__ xy_dw_w, const void* __restrict__ xy_dw_b,
    const void* __restrict__ zx_dw_w, const void* __restrict__ zx_dw_b,
    const void* __restrict__ zy_dw_w, const void* __restrict__ zy_dw_b,
    float* __restrict__ t_xy, float* __restrict__ t_zx, float* __restrict__ t_zy){
  const bool f32 = (flag[0] != 0);
  const float SC = 31.f/63.f;
  int id = blockIdx.x*256 + threadIdx.x;
  if (id < 32768){
    int c = id >> 12, rem = id & 4095, uu = rem >> 6, vv = rem & 63;
    float acc = ldf(xy_dw_b, c, f32);
    for (int du = 0; du < 3; du++){
      int ui = uu + du - 1; if (ui < 0 || ui >= 64) continue;
      float pu = ui*SC; int i0 = (int)pu; float wu = pu - (float)i0; int i1 = min(i0+1, 31);
      for (int dv = 0; dv < 3; dv++){
        int vi = vv + dv - 1; if (vi < 0 || vi >= 64) continue;
        float pv = vi*SC; int j0 = (int)pv; float wv = pv - (float)j0; int j1 = min(j0+1, 31);
        float s = ldf(p_xy, c*1024+i0*32+j0, f32)*(1.f-wu)*(1.f-wv) + ldf(p_xy, c*1024+i0*32+j1, f32)*(1.f-wu)*wv
                + ldf(p_xy, c*1024+i1*32+j0, f32)*wu*(1.f-wv)       + ldf(p_xy, c*1024+i1*32+j1, f32)*wu*wv;
        acc += ldf(xy_dw_w, c*9 + du*3 + dv, f32) * s;
      }
    }
    t_xy[id] = geluf(acc);
  } else if (id < 33280){
    int k = id - 32768; int c = k >> 6, a = k & 63;
    float acc = ldf(zx_dw_b, c, f32);
    for (int da = 0; da < 3; da++){
      int ai = a + da - 1; if (ai < 0 || ai >= 64) continue;
      float pa = ai*SC; int i0 = (int)pa; float wa = pa - (float)i0; int i1 = min(i0+1, 31);
      float s = ldf(p_zx, c*32+i0, f32)*(1.f-wa) + ldf(p_zx, c*32+i1, f32)*wa;
      acc += ldf(zx_dw_w, c*3+da, f32) * s;
    }
    t_zx[k] = geluf(acc);
  } else if (id < 33792){
    int k = id - 33280; int c = k >> 6, a = k & 63;
    float acc = ldf(zy_dw_b, c, f32);
    for (int da = 0; da < 3; da++){
      int ai = a + da - 1; if (ai < 0 || ai >= 64) continue;
      float pa = ai*SC; int i0 = (int)pa; float wa = pa - (float)i0; int i1 = min(i0+1, 31);
      float s = ldf(p_zy, c*32+i0, f32)*(1.f-wa) + ldf(p_zy, c*32+i1, f32)*wa;
      acc += ldf(zy_dw_w, c*3+da, f32) * s;
    }
    t_zy[k] = geluf(acc);
  }
}

// ---------------- multiplier chain stage 2 ----------------
__global__ __launch_bounds__(256) void k_mult2(const int* __restrict__ flag,
    const float* __restrict__ t_xy, const float* __restrict__ t_zx, const float* __restrict__ t_zy,
    const void* __restrict__ xy_pw_w, const void* __restrict__ xy_pw_b,
    const void* __restrict__ zx_pw_w, const void* __restrict__ zx_pw_b,
    const void* __restrict__ zy_pw_w, const void* __restrict__ zy_pw_b,
    float* __restrict__ kxy, float* __restrict__ kz, float* __restrict__ ky){
  const bool f32 = (flag[0] != 0);
  int id = blockIdx.x*256 + threadIdx.x;
  if (id < 32768){
    int oc = id >> 12, pix = id & 4095;
    float acc = ldf(xy_pw_b, oc, f32);
    #pragma unroll
    for (int ic = 0; ic < 8; ic++) acc += ldf(xy_pw_w, oc*8+ic, f32) * t_xy[ic*4096 + pix];
    kxy[id] = acc;
  } else if (id < 33280){
    int k = id - 32768; int oc = k >> 6, a = k & 63;
    float acc = ldf(zx_pw_b, oc, f32);
    #pragma unroll
    for (int ic = 0; ic < 8; ic++) acc += ldf(zx_pw_w, oc*8+ic, f32) * t_zx[ic*64 + a];
    kz[k] = acc;
  } else if (id < 33792){
    int k = id - 33280; int oc = k >> 6, a = k & 63;
    float acc = ldf(zy_pw_b, oc, f32);
    #pragma unroll
    for (int ic = 0; ic < 8; ic++) acc += ldf(zy_pw_w, oc*8+ic, f32) * t_zy[ic*64 + a];
    ky[k] = acc;
  }
}

// ---------------- fused G (r13: TB=8, 512 threads) ----------------
#define TB 8
#define W_M    0
#define W_R    32
#define W_G1   64
#define W_B1   96
#define W_G2   128
#define W_B2   160
#define W_LDWB 192
#define W_LPWB 224
#define W_PW   256
#define W_PWB  320
#define W_DW   328
#define W_DWB  400
#define W_LDW  408
#define W_TOT  696

template<bool F32>
__global__ __launch_bounds__(512) void k_g(const int* __restrict__ flag,
    const void* __restrict__ x,
    const void* n1g_, const void* n1b_, const void* n2g_, const void* n2b_,
    const void* dwpw_w, const void* dwpw_b, const void* dwdw_w, const void* dwdw_b,
    const void* ldw_dw_w, const void* ldw_dw_b, const void* ldw_pw_w, const void* ldw_pw_b,
    const float* __restrict__ meanH, const float* __restrict__ rstdH,
    const float* __restrict__ kxy, const float* __restrict__ kz, const float* __restrict__ ky,
    bf16* __restrict__ g){
  if (flag[0] != (F32 ? 1 : 0)) return;
  __shared__ unsigned short xs[32*10*64];
  __shared__ unsigned short t4g[8*12*64];
  __shared__ float muinv[2*10*64];
  __shared__ float sw[W_TOT];
  int n  = blockIdx.x >> 3;
  int a0 = (blockIdx.x & 7) * TB;
  int b = n & 1, h = n >> 1;
  int t = threadIdx.x;
  if (t < 32){
    sw[W_M+t]=meanH[b*32+t]; sw[W_R+t]=rstdH[b*32+t];
    sw[W_G1+t]=ldin<F32>(n1g_, t); sw[W_B1+t]=ldin<F32>(n1b_, t);
    sw[W_G2+t]=ldin<F32>(n2g_, t); sw[W_B2+t]=ldin<F32>(n2b_, t);
    sw[W_LDWB+t]=ldin<F32>(ldw_dw_b, t); sw[W_LPWB+t]=ldin<F32>(ldw_pw_b, t);
  }
  if (t >= 64 && t < 128) sw[W_PW+t-64]=ldin<F32>(dwpw_w, t-64);
  if (t >= 128 && t < 200) sw[W_DW+t-128]=ldin<F32>(dwdw_w, t-128);
  if (t >= 200 && t < 208) sw[W_PWB+t-200]=ldin<F32>(dwpw_b, t-200);
  if (t >= 208 && t < 216) sw[W_DWB+t-208]=ldin<F32>(dwdw_b, t-208);
  if (t >= 224 && t < 512){ int i = t - 224; sw[W_LDW+i] = ldin<F32>(ldw_dw_w, i); }
  __syncthreads();
  const float* s_g1 = sw+W_G1; const float* s_b1 = sw+W_B1;
  const float* s_g2 = sw+W_G2; const float* s_b2 = sw+W_B2;
  const size_t xbase = (size_t)b*64*SSS + (size_t)h*64;

  for (int i = t; i < 5120; i += 512){
    int c = i / 160, rem = i - c*160, row = rem >> 4, q = rem & 15;
    int a = a0 - 1 + row;
    unsigned short o0=0,o1=0,o2=0,o3=0;
    if (a >= 0 && a < 64){
      float m = sw[W_M+c], r = sw[W_R+c];
      size_t base = xbase + (size_t)c*SSS + (size_t)a*SS + q*4;
      if (F32){
        float4 v = *(const float4*)((const float*)x + base);
        o0=f2bu((v.x-m)*r); o1=f2bu((v.y-m)*r); o2=f2bu((v.z-m)*r); o3=f2bu((v.w-m)*r);
      } else {
        ushort4 v = *(const ushort4*)((const unsigned short*)x + base);
        o0=f2bu((u2f(v.x)-m)*r); o1=f2bu((u2f(v.y)-m)*r); o2=f2bu((u2f(v.z)-m)*r); o3=f2bu((u2f(v.w)-m)*r);
      }
    }
    ushort4 o4; o4.x=o0; o4.y=o1; o4.z=o2; o4.w=o3;
    *(ushort4*)&xs[(c*10+row)*64 + q*4] = o4;
  }
  __syncthreads();

  for (int p = t; p < 12*64; p += 512){
    int row = p >> 6, d = p & 63;
    int a = a0 - 2 + row;
    if (a < 0 || a >= 64){
      #pragma unroll
      for (int ic = 0; ic < 8; ic++) t4g[(ic*12+row)*64+d] = 0;
      continue;
    }
    float sum = 0.f, sq = 0.f; float z24[8];
    if (row >= 1 && row <= 10){
      int r10_ = row - 1;
      #pragma unroll
      for (int c = 0; c < 32; c++){
        float v = u2f(xs[(c*10+r10_)*64+d]); sum += v; sq += v*v;
        if (c >= 24) z24[c-24] = v;
      }
    } else {
      size_t xi = xbase + (size_t)a*SS + d;
      #pragma unroll
      for (int c = 0; c < 32; c++){
        float v = (ldin<F32>(x, xi + (size_t)c*SSS) - sw[W_M+c]) * sw[W_R+c];
        sum += v; sq += v*v;
        if (c >= 24) z24[c-24] = v;
      }
    }
    float mu = sum * (1.f/32.f);
    float inv = rsqrtf(sq*(1.f/32.f) - mu*mu + 1e-6f);
    if (row >= 1 && row <= 10){
      muinv[(row-1)*64+d] = mu; muinv[640 + (row-1)*64+d] = inv;
    }
    float zl[8];
    #pragma unroll
    for (int j = 0; j < 8; j++) zl[j] = (z24[j]-mu)*inv*s_g1[24+j] + s_b1[24+j];
    #pragma unroll
    for (int ic = 0; ic < 8; ic++){
      float acc = sw[W_PWB+ic];
      #pragma unroll
      for (int j = 0; j < 8; j++) acc += sw[W_PW+ic*8+j]*zl[j];
      t4g[(ic*12+row)*64+d] = f2bu(geluf(acc));
    }
  }
  __syncthreads();

  for (int p = t; p < 10*64; p += 512){
    int r2 = p >> 6, d = p & 63;
    int a = a0 - 1 + r2;
    if (a < 0 || a >= 64) continue;
    float mu = muinv[r2*64+d], inv = muinv[640 + r2*64+d];
    float s2 = 0.f, q2 = 0.f;
    #pragma unroll
    for (int c = 0; c < 8; c++){
      int idx = (c*10+r2)*64+d;
      float u = ((u2f(xs[idx])-mu)*inv*s_g1[c] + s_b1[c]) * kxy[(c*64 + a)*64 + d];
      xs[idx] = f2bu(u); s2 += u; q2 += u*u;
    }
    #pragma unroll
    for (int c = 8; c < 16; c++){
      int idx = (c*10+r2)*64+d;
      float u = ((u2f(xs[idx])-mu)*inv*s_g1[c] + s_b1[c]) * kz[(c-8)*64 + a];
      xs[idx] = f2bu(u); s2 += u; q2 += u*u;
    }
    #pragma unroll
    for (int c = 16; c < 24; c++){
      int idx = (c*10+r2)*64+d;
      float u = ((u2f(xs[idx])-mu)*inv*s_g1[c] + s_b1[c]) * ky[(c-16)*64 + d];
      xs[idx] = f2bu(u); s2 += u; q2 += u*u;
    }
    #pragma unroll
    for (int oc = 0; oc < 8; oc++){
      float acc = sw[W_DWB+oc];
      #pragma unroll
      for (int du = 0; du < 3; du++){
        #pragma unroll
        for (int dv = 0; dv < 3; dv++){
          int v2 = d + dv - 1;
          if (v2 >= 0 && v2 < 64) acc += sw[W_DW+oc*9+du*3+dv]*u2f(t4g[(oc*12+r2+du)*64+v2]);
        }
      }
      xs[((24+oc)*10+r2)*64+d] = f2bu(acc); s2 += acc; q2 += acc*acc;
    }
    float mu2 = s2 * (1.f/32.f);
    float inv2 = rsqrtf(q2*(1.f/32.f) - mu2*mu2 + 1e-6f);
    #pragma unroll
    for (int c = 0; c < 32; c++){
      int idx = (c*10+r2)*64+d;
      float uu = u2f(xs[idx]);
      xs[idx] = f2bu((uu-mu2)*inv2*s_g2[c] + s_b2[c]);
    }
  }
  __syncthreads();

  unsigned short* lpwB = t4g;
  unsigned short* gdXS = xs;
  for (int i = t; i < 1024; i += 512){
    int o = i >> 5, ic = i & 31;
    lpwB[o*40 + ic] = f2bu(ldin<F32>(ldw_pw_w, o*32+ic));
  }
  float gd[32];
  {
    int r = t >> 6, d = t & 63;
    #pragma unroll
    for (int oc = 0; oc < 32; oc++){
      float acc = sw[W_LDWB+oc];
      #pragma unroll
      for (int du = 0; du < 3; du++){
        #pragma unroll
        for (int dv = 0; dv < 3; dv++){
          int v2 = d + dv - 1;
          if (v2 >= 0 && v2 < 64) acc += sw[W_LDW+oc*9+du*3+dv]*u2f(xs[(oc*10+r+du)*64+v2]);
        }
      }
      gd[oc] = geluf(acc);
    }
  }
  __syncthreads();

  #pragma unroll
  for (int q = 0; q < 4; q++){
    unsigned short tmp8[8];
    #pragma unroll
    for (int j = 0; j < 8; j++) tmp8[j] = f2bu(gd[q*8+j]);
    *(short8*)&gdXS[t*40 + q*8] = *(const short8*)tmp8;
  }
  __syncthreads();

  {
    int wv = t >> 6, l = t & 63;
    int lr = l & 15, lg = l >> 4;
    #pragma unroll
    for (int mi = 0; mi < 4; mi++){
      int px0 = wv*64 + mi*16;
      short8 af = *(const short8*)&gdXS[(px0+lr)*40 + lg*8];
      #pragma unroll
      for (int ot = 0; ot < 2; ot++){
        short8 bf = *(const short8*)&lpwB[(ot*16+lr)*40 + lg*8];
        f32x4 c4 = {0.f,0.f,0.f,0.f};
        c4 = __builtin_amdgcn_mfma_f32_16x16x32_bf16(af, bf, c4, 0, 0, 0);
        int oc = ot*16 + lr;
        float bo = sw[W_LPWB+oc];
        #pragma unroll
        for (int r4 = 0; r4 < 4; r4++){
          int px = px0 + lg*4 + r4;
          int aa = a0 + (px >> 6), dd = px & 63;
          g[(size_t)n*131072 + (size_t)oc*4096 + aa*64 + dd] = f2b(c4[r4] + bo);
        }
      }
    }
  }
}

// ---------------- g-half stats2 partials ----------------
__global__ __launch_bounds__(256) void k_gstats(const bf16* __restrict__ g,
                                                float* __restrict__ partg){
  int pair = blockIdx.x >> 3, sp = blockIdx.x & 7;
  int b = pair >> 5, c = pair & 31;
  float s = 0.f, s2 = 0.f;
  for (int i = threadIdx.x; i < 32768; i += 256){
    int ii = sp*32768 + i;
    int d = ii & 63, w = (ii >> 6) & 63, h = ii >> 12;
    int n1 = h*2 + b, n2 = (63-h)*2 + b;
    float v = b2f(g[((size_t)n1*32 + c)*4096 + w*64 + d]) + b2f(g[((size_t)n2*32 + c)*4096 + w*64 + d]);
    s += v; s2 += v*v;
  }
  blk_reduce2(s, s2);
  if (threadIdx.x == 0){ partg[blockIdx.x*2] = s; partg[blockIdx.x*2+1] = s2; }
}

__global__ void k_gfinal(const float* __restrict__ partg,
                         float* __restrict__ mean2, float* __restrict__ rstd2){
  int t = threadIdx.x; if (t >= 64) return;
  float s = 0.f, s2 = 0.f;
  #pragma unroll
  for (int i = 0; i < 8; i++){ s += partg[(t*8+i)*2]; s2 += partg[(t*8+i)*2+1]; }
  float m = s * (1.f/262144.f);
  float var = s2 * (1.f/262144.f) - m*m;
  int b = t >> 5, c = t & 31;
  mean2[b*64+c] = m; rstd2[b*64+c] = rsqrtf(var + 1e-5f);
}

// ---------------- mprep ----------------
__global__ __launch_bounds__(256) void k_mprep(const int* __restrict__ flag,
    const void* __restrict__ fc1w, const void* __restrict__ fc1b,
    const void* __restrict__ fc2w, const void* __restrict__ fc2b,
    const float* __restrict__ mean2, const float* __restrict__ rstd2,
    unsigned short* __restrict__ W1p, unsigned short* __restrict__ W2b,
    float* __restrict__ b1p, float* __restrict__ b2p){
  const bool f32 = (flag[0] != 0);
  int gid = blockIdx.x*256 + threadIdx.x;
  for (int i = gid; i < 16384; i += 4096){
    int bb = i >> 13, r = i & 8191, c = r & 63;
    W1p[i] = f2bu(ldf(fc1w, r, f32) * rstd2[bb*64+c]);
  }
  for (int i = gid; i < 8192; i += 4096) W2b[i] = f2bu(ldf(fc2w, i, f32));
  if (gid < 256){
    int bb = gid >> 7, j = gid & 127;
    float s = ldf(fc1b, j, f32);
    for (int c = 0; c < 64; c++) s -= ldf(fc1w, j*64+c, f32) * mean2[bb*64+c] * rstd2[bb*64+c];
    b1p[gid] = s;
  }
  if (gid < 64) b2p[gid] = ldf(fc2b, gid, f32);
}

// ---------------- MFMA MLP v2: 2 pixel-tiles (256 px) per block ----------------
// LDS layout: [w1s 18432 | w2s 17408 | zs/hb 18432] = 54272. obuf (33024) overlays
// the WEIGHTS region, used only after all compute. hb overlays zs (per-wave).
__global__ __launch_bounds__(256) void k_mlp(const int* __restrict__ flag,
    const void* __restrict__ x, const bf16* __restrict__ g,
    const unsigned short* __restrict__ W1p, const unsigned short* __restrict__ W2b,
    const float* __restrict__ b1p, const float* __restrict__ b2p,
    void* __restrict__ out){
  const bool f32 = (flag[0] != 0);
  __shared__ char smem[54272];
  unsigned short* w1s = (unsigned short*)smem;            // [128][72]
  unsigned short* w2s = (unsigned short*)(smem+18432);    // [64][136]
  unsigned short* zs  = (unsigned short*)(smem+35840);    // [128][72]
  unsigned short* hb  = zs;                               // overlay zs (per-wave regions)
  float* obuf = (float*)smem;                             // [64][129] f32, after compute
  int blk = blockIdx.x;
  int b = blk >> 10, w = (blk >> 4) & 63, hblk = blk & 15;
  int t = threadIdx.x;
  int wv = t >> 6, l = t & 63;
  int lr = l & 15, lg = l >> 4;

  // stage weights once per 256 px
  const unsigned short* W1g = W1p + b*8192;
  for (int i = t; i < 1024; i += 256){
    int j = i >> 3, q = i & 7;
    *(short8*)&w1s[j*72 + q*8] = *(const short8*)&W1g[j*64 + q*8];
  }
  for (int i = t; i < 1024; i += 256){
    int o = i >> 4, q = i & 15;
    *(short8*)&w2s[o*136 + q*8] = *(const short8*)&W2b[o*128 + q*8];
  }
  float bj_r[8], bo_r[4];
  #pragma unroll
  for (int jt = 0; jt < 8; jt++) bj_r[jt] = b1p[b*128 + jt*16 + lr];
  #pragma unroll
  for (int ot = 0; ot < 4; ot++) bo_r[ot] = b2p[ot*16 + lr];

  float ov[2][2][4][4];
  unsigned short* hbw = &hb[wv*16*136];

  #pragma unroll
  for (int it = 0; it < 2; it++){
    int h0 = hblk*4 + it*2;
    if (it == 1) __syncthreads();   // hb(it0) dead across all waves before re-staging zs
    // stage z_raw for 128 px at h0
    {
      int px = t & 127, half = t >> 7;
      int hh = px >> 6, d = px & 63;
      int h = h0 + hh;
      unsigned short tmp[32];
      if (half == 0){
        int n1 = h*2 + b, n2 = (63-h)*2 + b;
        const bf16* g1 = g + ((size_t)n1*32)*4096 + w*64 + d;
        const bf16* g2 = g + ((size_t)n2*32)*4096 + w*64 + d;
        #pragma unroll
        for (int c = 0; c < 32; c++) tmp[c] = f2bu(b2f(g1[(size_t)c*4096]) + b2f(g2[(size_t)c*4096]));
      } else {
        size_t xi = ((size_t)(b*64+32))*SSS + (size_t)w*4096 + (size_t)h*64 + d;
        if (f32){
          const float* xp = (const float*)x;
          #pragma unroll
          for (int c = 0; c < 32; c++) tmp[c] = f2bu(xp[xi + (size_t)c*SSS]);
        } else {
          const unsigned short* xp = (const unsigned short*)x;
          #pragma unroll
          for (int c = 0; c < 32; c++) tmp[c] = xp[xi + (size_t)c*SSS];
        }
      }
      short8* dst = (short8*)&zs[px*72 + half*32];
      #pragma unroll
      for (int q = 0; q < 4; q++) dst[q] = *(short8*)&tmp[q*8];
    }
    __syncthreads();

    // prefetch A-fragments for both M-tiles -> zs dead
    short8 a0f[2], a1f[2];
    #pragma unroll
    for (int mi = 0; mi < 2; mi++){
      int px0 = wv*32 + mi*16;
      a0f[mi] = *(const short8*)&zs[(px0+lr)*72 + lg*8];
      a1f[mi] = *(const short8*)&zs[(px0+lr)*72 + 32 + lg*8];
    }
    __syncthreads();

    #pragma unroll
    for (int mi = 0; mi < 2; mi++){
      f32x4 acc[8];
      #pragma unroll
      for (int jt = 0; jt < 8; jt++){
        short8 b0 = *(const short8*)&w1s[(jt*16+lr)*72 + lg*8];
        short8 b1 = *(const short8*)&w1s[(jt*16+lr)*72 + 32 + lg*8];
        f32x4 c4 = {0.f,0.f,0.f,0.f};
        c4 = __builtin_amdgcn_mfma_f32_16x16x32_bf16(a0f[mi], b0, c4, 0, 0, 0);
        c4 = __builtin_amdgcn_mfma_f32_16x16x32_bf16(a1f[mi], b1, c4, 0, 0, 0);
        acc[jt] = c4;
      }
      #pragma unroll
      for (int jt = 0; jt < 8; jt++){
        float bj = bj_r[jt];
        #pragma unroll
        for (int r = 0; r < 4; r++){
          hbw[(lg*4+r)*136 + jt*16 + lr] = f2bu(geluf(acc[jt][r] + bj));
        }
      }
      short8 ha[4];
      #pragma unroll
      for (int m = 0; m < 4; m++) ha[m] = *(const short8*)&hbw[lr*136 + m*32 + lg*8];
      #pragma unroll
      for (int ot = 0; ot < 4; ot++){
        f32x4 c4 = {0.f,0.f,0.f,0.f};
        #pragma unroll
        for (int m = 0; m < 4; m++){
          short8 bb = *(const short8*)&w2s[(ot*16+lr)*136 + m*32 + lg*8];
          c4 = __builtin_amdgcn_mfma_f32_16x16x32_bf16(ha[m], bb, c4, 0, 0, 0);
        }
        #pragma unroll
        for (int r4 = 0; r4 < 4; r4++) ov[it][mi][ot][r4] = c4[r4];
      }
    }
  }
  __syncthreads();   // all compute done -> weights dead -> obuf may overlay

  #pragma unroll
  for (int it = 0; it < 2; it++){
    int h0 = hblk*4 + it*2;
    #pragma unroll
    for (int mi = 0; mi < 2; mi++){
      int px0 = wv*32 + mi*16;
      #pragma unroll
      for (int ot = 0; ot < 4; ot++){
        float bo = bo_r[ot];
        int oc = ot*16 + lr;
        #pragma unroll
        for (int r4 = 0; r4 < 4; r4++){
          obuf[oc*129 + px0 + lg*4 + r4] = ov[it][mi][ot][r4] + bo;
        }
      }
    }
    __syncthreads();
    {
      int oc = t >> 2, ch = t & 3;
      size_t base = ((size_t)(b*64+oc))*SSS + (size_t)w*4096 + (size_t)h0*64 + ch*32;
      const float* src = &obuf[oc*129 + ch*32];
      if (f32){
        float* op = (float*)out;
        #pragma unroll
        for (int k = 0; k < 8; k++){
          float4 v; v.x = src[k*4]; v.y = src[k*4+1]; v.z = src[k*4+2]; v.w = src[k*4+3];
          *(float4*)&op[base + k*4] = v;
        }
      } else {
        bf16* op = (bf16*)out;
        #pragma unroll
        for (int k = 0; k < 4; k++){
          unsigned short tmp8[8];
          #pragma unroll
          for (int j = 0; j < 8; j++) tmp8[j] = f2bu(src[k*8+j]);
          *(short8*)&op[base + k*8] = *(const short8*)tmp8;
        }
      }
    }
    __syncthreads();
  }
}

extern "C" void kernel_launch(void* const* d_in, const int* in_sizes, int n_in,
                              void* d_out, int out_size, void* d_ws, size_t ws_size,
                              hipStream_t stream) {
  const void* X      = d_in[0];
  const void* n1g    = d_in[1];
  const void* n1b    = d_in[2];
  const void* n2g    = d_in[3];
  const void* n2b    = d_in[4];
  const void* p_xy   = d_in[5];
  const void* p_zx   = d_in[6];
  const void* p_zy   = d_in[7];
  const void* xy_dw_w= d_in[8];
  const void* xy_dw_b= d_in[9];
  const void* xy_pw_w= d_in[10];
  const void* xy_pw_b= d_in[11];
  const void* zx_dw_w= d_in[12];
  const void* zx_dw_b= d_in[13];
  const void* zx_pw_w= d_in[14];
  const void* zx_pw_b= d_in[15];
  const void* zy_dw_w= d_in[16];
  const void* zy_dw_b= d_in[17];
  const void* zy_pw_w= d_in[18];
  const void* zy_pw_b= d_in[19];
  const void* dw_pw_w= d_in[20];
  const void* dw_pw_b= d_in[21];
  const void* dw_dw_w= d_in[22];
  const void* dw_dw_b= d_in[23];
  const void* ldw_dw_w=d_in[24];
  const void* ldw_dw_b=d_in[25];
  const void* ldw_pw_w=d_in[26];
  const void* ldw_pw_b=d_in[27];
  const void* fc1w   = d_in[28];
  const void* fc1b   = d_in[29];
  const void* fc2w   = d_in[30];
  const void* fc2b   = d_in[31];

  int*  flag = (int*)d_ws;
  bf16* g    = (bf16*)((char*)d_ws + 16);
  float* fb  = (float*)((char*)d_ws + 16 + (size_t)16777216*2);
  float* meanH = fb;
  float* rstdH = fb + 64;
  float* t_xy  = fb + 128;
  float* t_zx  = fb + 32896;
  float* t_zy  = fb + 33408;
  float* kxy   = fb + 33920;
  float* kz    = fb + 66688;
  float* ky    = fb + 67200;
  float* mean2 = fb + 67712;
  float* rstd2 = fb + 67840;
  float* part  = fb + 67968;
  float* partg = fb + 70016;
  float* b1p   = fb + 71040;
  float* b2p   = fb + 71296;
  unsigned short* W1p = (unsigned short*)(fb + 71360);
  unsigned short* W2b = (unsigned short*)(fb + 79552);

  k_probe<<<1, 64, 0, stream>>>((const unsigned short*)X, flag);
  k_cstats<<<1024, 256, 0, stream>>>(flag, X, part);
  k_sfinal<<<1, 128, 0, stream>>>(part, meanH, rstdH, mean2, rstd2);
  k_mult1<<<132, 256, 0, stream>>>(flag, p_xy, p_zx, p_zy, xy_dw_w, xy_dw_b,
                                   zx_dw_w, zx_dw_b, zy_dw_w, zy_dw_b, t_xy, t_zx, t_zy);
  k_mult2<<<132, 256, 0, stream>>>(flag, t_xy, t_zx, t_zy, xy_pw_w, xy_pw_b,
                                   zx_pw_w, zx_pw_b, zy_pw_w, zy_pw_b, kxy, kz, ky);
  k_g<false><<<128*(64/TB), 512, 0, stream>>>(flag, X, n1g, n1b, n2g, n2b,
                                       dw_pw_w, dw_pw_b, dw_dw_w, dw_dw_b,
                                       ldw_dw_w, ldw_dw_b, ldw_pw_w, ldw_pw_b,
                                       meanH, rstdH, kxy, kz, ky, g);
  k_g<true ><<<128*(64/TB), 512, 0, stream>>>(flag, X, n1g, n1b, n2g, n2b,
                                       dw_pw_w, dw_pw_b, dw_dw_w, dw_dw_b,
                                       ldw_dw_w, ldw_dw_b, ldw_pw_w, ldw_pw_b,
                                       meanH, rstdH, kxy, kz, ky, g);
  k_gstats<<<512, 256, 0, stream>>>(g, partg);
  k_gfinal<<<1, 64, 0, stream>>>(partg, mean2, rstd2);
  k_mprep<<<16, 256, 0, stream>>>(flag, fc1w, fc1b, fc2w, fc2b, mean2, rstd2,
                                  W1p, W2b, b1p, b2p);
  k_mlp<<<2048, 256, 0, stream>>>(flag, X, g, W1p, W2b, b1p, b2p, d_out);
}